// Round 1
// baseline (898.604 us; speedup 1.0000x reference)
//
#include <hip/hip_runtime.h>

#define N_NODES 50000
#define N_EDGES 1600000

typedef __attribute__((ext_vector_type(4))) float f32x4;
typedef __attribute__((ext_vector_type(8))) short bf16x8;

__device__ __forceinline__ float lrelu(float x) { return x >= 0.f ? x : 0.01f * x; }

// f32 -> bf16 with round-to-nearest-even (bit trick)
__device__ __forceinline__ unsigned short f2bf(float f) {
    union { float f; unsigned u; } v; v.f = f;
    unsigned u = v.u;
    u += 0x7fffu + ((u >> 16) & 1u);
    return (unsigned short)(u >> 16);
}

// ---------------------------------------------------------------------------
// k1: h1 = lrelu(x @ lin1_w.T + lin1_b)   [50000,2048]x[128,2048]^T -> [50000,128]
// bf16 MFMA 16x16x32, BM=64 (4 waves x 16 rows), full N=128, BK=64.
// LDS tiles XOR-swizzled at 8-element granularity to kill ds_read_b128 bank
// conflicts (stride-128B rows would be 16-way).
// ---------------------------------------------------------------------------
__launch_bounds__(256)
__global__ void k_lin1(const float* __restrict__ X, const float* __restrict__ W,
                       const float* __restrict__ Bv, float* __restrict__ H)
{
    __shared__ __align__(16) unsigned short As[64 * 64];
    __shared__ __align__(16) unsigned short Bs[128 * 64];

    const int t = threadIdx.x;
    const int wave = t >> 6, lane = t & 63;
    const int lrow = lane & 15, lgrp = lane >> 4;
    const int m0 = blockIdx.x * 64;

    f32x4 acc[8];
#pragma unroll
    for (int i = 0; i < 8; i++) acc[i] = (f32x4)0.f;

    for (int kc = 0; kc < 2048; kc += 64) {
        // stage A tile: 64 rows x 64 k (f32 -> bf16)
#pragma unroll
        for (int u = 0; u < 4; u++) {
            int idx = t + 256 * u;
            int r = idx >> 4, g = idx & 15;
            int gr = m0 + r;
            float4 v = make_float4(0.f, 0.f, 0.f, 0.f);
            if (gr < N_NODES) v = *(const float4*)(X + (size_t)gr * 2048 + kc + 4 * g);
            ushort4 b;
            b.x = f2bf(v.x); b.y = f2bf(v.y); b.z = f2bf(v.z); b.w = f2bf(v.w);
            int e = r * 64 + ((4 * g) ^ ((r & 7) << 3));
            *(ushort4*)(As + e) = b;
        }
        // stage B tile: 128 n x 64 k
#pragma unroll
        for (int u = 0; u < 8; u++) {
            int idx = t + 256 * u;
            int n = idx >> 4, g = idx & 15;
            float4 v = *(const float4*)(W + (size_t)n * 2048 + kc + 4 * g);
            ushort4 b;
            b.x = f2bf(v.x); b.y = f2bf(v.y); b.z = f2bf(v.z); b.w = f2bf(v.w);
            int e = n * 64 + ((4 * g) ^ ((n & 7) << 3));
            *(ushort4*)(Bs + e) = b;
        }
        __syncthreads();

#pragma unroll
        for (int ks = 0; ks < 2; ks++) {
            const int kbase = ks * 32 + 8 * lgrp;       // 8-aligned
            const int ar = wave * 16 + lrow;
            bf16x8 a = *(const bf16x8*)(As + ar * 64 + (kbase ^ ((ar & 7) << 3)));
#pragma unroll
            for (int nf = 0; nf < 8; nf++) {
                const int bn = nf * 16 + lrow;
                bf16x8 bb = *(const bf16x8*)(Bs + bn * 64 + (kbase ^ ((bn & 7) << 3)));
                acc[nf] = __builtin_amdgcn_mfma_f32_16x16x32_bf16(a, bb, acc[nf], 0, 0, 0);
            }
        }
        __syncthreads();
    }

    // epilogue: bias + lrelu, C/D layout col=lane&15, row=(lane>>4)*4+reg
#pragma unroll
    for (int nf = 0; nf < 8; nf++) {
        const int col = nf * 16 + lrow;
        const float bias = Bv[col];
#pragma unroll
        for (int r = 0; r < 4; r++) {
            const int row = m0 + wave * 16 + lgrp * 4 + r;
            if (row < N_NODES)
                H[(size_t)row * 128 + col] = lrelu(acc[nf][r] + bias);
        }
    }
}

// ---------------------------------------------------------------------------
// k_dual: per node, t = in @ Wrel.T ; accout = in @ Wroot.T + bias
// (optionally lrelu applied to the input row on read).
// Wave-per-node; concatenated weights [Wrel;Wroot] staged in LDS with
// k ^ (j&31) swizzle so 64 lanes reading column k of distinct rows are
// conflict-free.
// ---------------------------------------------------------------------------
template <int F_IN, int F_OUT, bool LRELU_IN>
__launch_bounds__(256)
__global__ void k_dual(const float* __restrict__ in, const float* __restrict__ Wrel,
                       const float* __restrict__ Wroot, const float* __restrict__ bias,
                       float* __restrict__ tout, float* __restrict__ accout)
{
    __shared__ float Wl[2 * F_OUT * F_IN];
    const int t = threadIdx.x;

    for (int idx = t; idx < 2 * F_OUT * F_IN; idx += 256) {
        int j = idx / F_IN, k = idx % F_IN;
        float v = (j < F_OUT) ? Wrel[j * F_IN + k] : Wroot[(j - F_OUT) * F_IN + k];
        Wl[j * F_IN + (k ^ (j & 31))] = v;
    }
    __syncthreads();

    const int lane = t & 63;
    const int wid = (blockIdx.x << 2) | (t >> 6);
    const int nwaves = gridDim.x << 2;

    for (int node = wid; node < N_NODES; node += nwaves) {
        const int snode = __builtin_amdgcn_readfirstlane(node);
        const float* row = in + (size_t)snode * F_IN;

        if constexpr (F_OUT == 64) {
            const int j0 = lane, j1 = lane + 64;
            const float* w0 = Wl + j0 * F_IN; const int x0 = j0 & 31;
            const float* w1 = Wl + j1 * F_IN; const int x1 = j1 & 31;
            float a0 = 0.f, a1 = 0.f;
#pragma unroll 8
            for (int k = 0; k < F_IN; k++) {
                float r = row[k];
                if (LRELU_IN) r = lrelu(r);
                a0 += r * w0[k ^ x0];
                a1 += r * w1[k ^ x1];
            }
            tout[(size_t)snode * 64 + lane] = a0;
            accout[(size_t)snode * 64 + lane] = a1 + bias[lane];
        } else {  // F_OUT == 32: lanes 0..31 -> Wrel row l, lanes 32..63 -> Wroot row l-32
            const int j = lane;
            const float* w0 = Wl + j * F_IN; const int x0 = j & 31;
            float a0 = 0.f;
#pragma unroll 8
            for (int k = 0; k < F_IN; k++) {
                float r = row[k];
                if (LRELU_IN) r = lrelu(r);
                a0 += r * w0[k ^ x0];
            }
            if (lane < 32) tout[(size_t)snode * 32 + lane] = a0;
            else           accout[(size_t)snode * 32 + (lane - 32)] = a0 + bias[lane - 32];
        }
    }
}

// ---------------------------------------------------------------------------
// k_scatter: acc[dst] += t[src] for every edge (feature-parallel, f32 atomics).
// tid -> (edge, feature); edge index reads are wave-uniform (broadcast).
// ---------------------------------------------------------------------------
template <int LOGF>
__launch_bounds__(256)
__global__ void k_scatter(const int* __restrict__ ei, const float* __restrict__ t,
                          float* __restrict__ acc)
{
    const int total = N_EDGES << LOGF;
    const int stride = gridDim.x * 256;
    for (int i = blockIdx.x * 256 + threadIdx.x; i < total; i += stride) {
        const int e = i >> LOGF;
        const int f = i & ((1 << LOGF) - 1);
        const int src = ei[e];
        const int dst = ei[N_EDGES + e];
        atomicAdd(acc + ((size_t)dst << LOGF) + f, t[((size_t)src << LOGF) + f]);
    }
}

// ---------------------------------------------------------------------------
// k_pos: out = lrelu(acc2) @ pos_w.T + pos_b   [50000,32] -> [50000,3]
// ---------------------------------------------------------------------------
__launch_bounds__(256)
__global__ void k_pos(const float* __restrict__ acc2, const float* __restrict__ PW,
                      const float* __restrict__ PB, float* __restrict__ out)
{
    const int n = blockIdx.x * 256 + threadIdx.x;
    if (n >= N_NODES) return;
    float h[32];
    const float4* rp = (const float4*)(acc2 + (size_t)n * 32);
#pragma unroll
    for (int i = 0; i < 8; i++) {
        float4 v = rp[i];
        h[4 * i + 0] = lrelu(v.x);
        h[4 * i + 1] = lrelu(v.y);
        h[4 * i + 2] = lrelu(v.z);
        h[4 * i + 3] = lrelu(v.w);
    }
#pragma unroll
    for (int c = 0; c < 3; c++) {
        float s = PB[c];
#pragma unroll
        for (int k = 0; k < 32; k++) s += h[k] * PW[c * 32 + k];
        out[(size_t)n * 3 + c] = s;
    }
}

// ---------------------------------------------------------------------------
extern "C" void kernel_launch(void* const* d_in, const int* in_sizes, int n_in,
                              void* d_out, int out_size, void* d_ws, size_t ws_size,
                              hipStream_t stream)
{
    const float* x        = (const float*)d_in[0];
    const int*   ei       = (const int*)d_in[1];
    const float* lin1_w   = (const float*)d_in[2];
    const float* lin1_b   = (const float*)d_in[3];
    const float* c1_wrel  = (const float*)d_in[4];
    const float* c1_brel  = (const float*)d_in[5];
    const float* c1_wroot = (const float*)d_in[6];
    const float* c4_wrel  = (const float*)d_in[7];
    const float* c4_brel  = (const float*)d_in[8];
    const float* c4_wroot = (const float*)d_in[9];
    const float* pos_w    = (const float*)d_in[10];
    const float* pos_b    = (const float*)d_in[11];
    float* out = (float*)d_out;

    float* h1   = (float*)d_ws;                    // 50000*128 f32 = 25.6 MB
    float* t1   = h1   + (size_t)N_NODES * 128;    // 50000*64   = 12.8 MB
    float* acc1 = t1   + (size_t)N_NODES * 64;     // 50000*64   = 12.8 MB
    float* t2   = acc1 + (size_t)N_NODES * 64;     // 50000*32   = 6.4 MB
    float* acc2 = t2   + (size_t)N_NODES * 32;     // 50000*32   = 6.4 MB

    // 1) h1 = lrelu(x @ lin1_w.T + b)
    hipLaunchKernelGGL(k_lin1, dim3((N_NODES + 63) / 64), dim3(256), 0, stream,
                       x, lin1_w, lin1_b, h1);
    // 2) t1 = h1 @ c1_wrel.T ; acc1 = h1 @ c1_wroot.T + b_rel
    hipLaunchKernelGGL((k_dual<128, 64, false>), dim3(768), dim3(256), 0, stream,
                       h1, c1_wrel, c1_wroot, c1_brel, t1, acc1);
    // 3) acc1[dst] += t1[src]  (segment_sum pushed through the linear map)
    hipLaunchKernelGGL((k_scatter<6>), dim3(32768), dim3(256), 0, stream, ei, t1, acc1);
    // 4) t2 = lrelu(acc1) @ c4_wrel.T ; acc2 = lrelu(acc1) @ c4_wroot.T + b_rel
    hipLaunchKernelGGL((k_dual<64, 32, true>), dim3(768), dim3(256), 0, stream,
                       acc1, c4_wrel, c4_wroot, c4_brel, t2, acc2);
    // 5) acc2[dst] += t2[src]
    hipLaunchKernelGGL((k_scatter<5>), dim3(16384), dim3(256), 0, stream, ei, t2, acc2);
    // 6) out = lrelu(acc2) @ pos_w.T + pos_b
    hipLaunchKernelGGL(k_pos, dim3((N_NODES + 255) / 256), dim3(256), 0, stream,
                       acc2, pos_w, pos_b, out);
}

// Round 2
// 713.952 us; speedup vs baseline: 1.2586x; 1.2586x over previous
//
#include <hip/hip_runtime.h>

#define N_NODES 50000
#define N_EDGES 1600000

typedef __attribute__((ext_vector_type(4))) float f32x4;
typedef __attribute__((ext_vector_type(8))) short bf16x8;

__device__ __forceinline__ float lrelu(float x) { return x >= 0.f ? x : 0.01f * x; }

// f32 -> bf16 round-to-nearest-even
__device__ __forceinline__ unsigned short f2bf(float f) {
    union { float f; unsigned u; } v; v.f = f;
    unsigned u = v.u;
    u += 0x7fffu + ((u >> 16) & 1u);
    return (unsigned short)(u >> 16);
}

// ---------------------------------------------------------------------------
// k_lin1: h1 = lrelu(x @ lin1_w.T + b)  via bf16 MFMA 16x16x32 (unchanged)
// ---------------------------------------------------------------------------
__launch_bounds__(256)
__global__ void k_lin1(const float* __restrict__ X, const float* __restrict__ W,
                       const float* __restrict__ Bv, float* __restrict__ H)
{
    __shared__ __align__(16) unsigned short As[64 * 64];
    __shared__ __align__(16) unsigned short Bs[128 * 64];

    const int t = threadIdx.x;
    const int wave = t >> 6, lane = t & 63;
    const int lrow = lane & 15, lgrp = lane >> 4;
    const int m0 = blockIdx.x * 64;

    f32x4 acc[8];
#pragma unroll
    for (int i = 0; i < 8; i++) acc[i] = (f32x4)0.f;

    for (int kc = 0; kc < 2048; kc += 64) {
#pragma unroll
        for (int u = 0; u < 4; u++) {
            int idx = t + 256 * u;
            int r = idx >> 4, g = idx & 15;
            int gr = m0 + r;
            float4 v = make_float4(0.f, 0.f, 0.f, 0.f);
            if (gr < N_NODES) v = *(const float4*)(X + (size_t)gr * 2048 + kc + 4 * g);
            ushort4 b;
            b.x = f2bf(v.x); b.y = f2bf(v.y); b.z = f2bf(v.z); b.w = f2bf(v.w);
            int e = r * 64 + ((4 * g) ^ ((r & 7) << 3));
            *(ushort4*)(As + e) = b;
        }
#pragma unroll
        for (int u = 0; u < 8; u++) {
            int idx = t + 256 * u;
            int n = idx >> 4, g = idx & 15;
            float4 v = *(const float4*)(W + (size_t)n * 2048 + kc + 4 * g);
            ushort4 b;
            b.x = f2bf(v.x); b.y = f2bf(v.y); b.z = f2bf(v.z); b.w = f2bf(v.w);
            int e = n * 64 + ((4 * g) ^ ((n & 7) << 3));
            *(ushort4*)(Bs + e) = b;
        }
        __syncthreads();

#pragma unroll
        for (int ks = 0; ks < 2; ks++) {
            const int kbase = ks * 32 + 8 * lgrp;
            const int ar = wave * 16 + lrow;
            bf16x8 a = *(const bf16x8*)(As + ar * 64 + (kbase ^ ((ar & 7) << 3)));
#pragma unroll
            for (int nf = 0; nf < 8; nf++) {
                const int bn = nf * 16 + lrow;
                bf16x8 bb = *(const bf16x8*)(Bs + bn * 64 + (kbase ^ ((bn & 7) << 3)));
                acc[nf] = __builtin_amdgcn_mfma_f32_16x16x32_bf16(a, bb, acc[nf], 0, 0, 0);
            }
        }
        __syncthreads();
    }

#pragma unroll
    for (int nf = 0; nf < 8; nf++) {
        const int col = nf * 16 + lrow;
        const float bias = Bv[col];
#pragma unroll
        for (int r = 0; r < 4; r++) {
            const int row = m0 + wave * 16 + lgrp * 4 + r;
            if (row < N_NODES)
                H[(size_t)row * 128 + col] = lrelu(acc[nf][r] + bias);
        }
    }
}

// ---------------------------------------------------------------------------
// k_dual: per node, tout = in @ Wrel.T ; accout = in @ Wroot.T + bias
// ---------------------------------------------------------------------------
template <int F_IN, int F_OUT, bool LRELU_IN>
__launch_bounds__(256)
__global__ void k_dual(const float* __restrict__ in, const float* __restrict__ Wrel,
                       const float* __restrict__ Wroot, const float* __restrict__ bias,
                       float* __restrict__ tout, float* __restrict__ accout)
{
    __shared__ float Wl[2 * F_OUT * F_IN];
    const int t = threadIdx.x;

    for (int idx = t; idx < 2 * F_OUT * F_IN; idx += 256) {
        int j = idx / F_IN, k = idx % F_IN;
        float v = (j < F_OUT) ? Wrel[j * F_IN + k] : Wroot[(j - F_OUT) * F_IN + k];
        Wl[j * F_IN + (k ^ (j & 31))] = v;
    }
    __syncthreads();

    const int lane = t & 63;
    const int wid = (blockIdx.x << 2) | (t >> 6);
    const int nwaves = gridDim.x << 2;

    for (int node = wid; node < N_NODES; node += nwaves) {
        const int snode = __builtin_amdgcn_readfirstlane(node);
        const float* row = in + (size_t)snode * F_IN;

        if constexpr (F_OUT == 64) {
            const int j0 = lane, j1 = lane + 64;
            const float* w0 = Wl + j0 * F_IN; const int x0 = j0 & 31;
            const float* w1 = Wl + j1 * F_IN; const int x1 = j1 & 31;
            float a0 = 0.f, a1 = 0.f;
#pragma unroll 8
            for (int k = 0; k < F_IN; k++) {
                float r = row[k];
                if (LRELU_IN) r = lrelu(r);
                a0 += r * w0[k ^ x0];
                a1 += r * w1[k ^ x1];
            }
            tout[(size_t)snode * 64 + lane] = a0;
            accout[(size_t)snode * 64 + lane] = a1 + bias[lane];
        } else {
            const int j = lane;
            const float* w0 = Wl + j * F_IN; const int x0 = j & 31;
            float a0 = 0.f;
#pragma unroll 8
            for (int k = 0; k < F_IN; k++) {
                float r = row[k];
                if (LRELU_IN) r = lrelu(r);
                a0 += r * w0[k ^ x0];
            }
            if (lane < 32) tout[(size_t)snode * 32 + lane] = a0;
            else           accout[(size_t)snode * 32 + (lane - 32)] = a0 + bias[lane - 32];
        }
    }
}

// ---------------------------------------------------------------------------
// CSR build: zero -> hist -> scan1 -> scan2 -> scan3 -> fill
// ---------------------------------------------------------------------------
__launch_bounds__(256)
__global__ void k_zero(int* __restrict__ p, int n)
{
    int i = blockIdx.x * 256 + threadIdx.x;
    if (i < n) p[i] = 0;
}

__launch_bounds__(256)
__global__ void k_hist(const int* __restrict__ ei, int* __restrict__ deg)
{
    const int stride = gridDim.x * 256;
    for (int e = blockIdx.x * 256 + threadIdx.x; e < N_EDGES; e += stride)
        atomicAdd(deg + ei[N_EDGES + e], 1);
}

__launch_bounds__(256)
__global__ void k_scan1(const int* __restrict__ deg, int* __restrict__ tmp,
                        int* __restrict__ bsum)
{
    __shared__ int sm[256];
    const int tid = threadIdx.x;
    const int i = blockIdx.x * 256 + tid;
    int d = (i < N_NODES) ? deg[i] : 0;
    sm[tid] = d;
    __syncthreads();
#pragma unroll
    for (int off = 1; off < 256; off <<= 1) {
        int v = (tid >= off) ? sm[tid - off] : 0;
        __syncthreads();
        sm[tid] += v;
        __syncthreads();
    }
    if (i < N_NODES) tmp[i] = sm[tid];
    if (tid == 255) bsum[blockIdx.x] = sm[255];
}

__global__ void k_scan2(const int* __restrict__ bsum, int* __restrict__ boff, int nb)
{
    if (threadIdx.x == 0 && blockIdx.x == 0) {
        int run = 0;
        for (int b = 0; b < nb; b++) { boff[b] = run; run += bsum[b]; }
    }
}

__launch_bounds__(256)
__global__ void k_scan3(const int* __restrict__ tmp, const int* __restrict__ boff,
                        const int* __restrict__ deg, int* __restrict__ ro,
                        int* __restrict__ cur)
{
    const int i = blockIdx.x * 256 + threadIdx.x;
    if (i < N_NODES) {
        int incl = tmp[i] + boff[i >> 8];
        ro[i + 1] = incl;
        cur[i] = incl - deg[i];
    }
    if (i == 0) ro[0] = 0;
}

__launch_bounds__(256)
__global__ void k_fill(const int* __restrict__ ei, int* __restrict__ cur,
                       int* __restrict__ csr)
{
    const int stride = gridDim.x * 256;
    for (int e = blockIdx.x * 256 + threadIdx.x; e < N_EDGES; e += stride) {
        const int dst = ei[N_EDGES + e];
        const int p = atomicAdd(cur + dst, 1);
        csr[p] = ei[e];
    }
}

// ---------------------------------------------------------------------------
// k_gather64: acc[n] += sum over in-edges of t[src], wave per node, lane=feature
// ---------------------------------------------------------------------------
__launch_bounds__(256)
__global__ void k_gather64(const int* __restrict__ ro, const int* __restrict__ csr,
                           const float* __restrict__ t, float* __restrict__ acc)
{
    const int wid = (blockIdx.x << 2) | (threadIdx.x >> 6);
    if (wid >= N_NODES) return;
    const int lane = threadIdx.x & 63;
    const int s = ro[wid], e = ro[wid + 1];
    float a = acc[(size_t)wid * 64 + lane];
    int i = s;
    for (; i + 4 <= e; i += 4) {
        int s0 = csr[i], s1 = csr[i + 1], s2 = csr[i + 2], s3 = csr[i + 3];
        float v0 = t[(size_t)s0 * 64 + lane];
        float v1 = t[(size_t)s1 * 64 + lane];
        float v2 = t[(size_t)s2 * 64 + lane];
        float v3 = t[(size_t)s3 * 64 + lane];
        a += v0; a += v1; a += v2; a += v3;
    }
    for (; i < e; ++i) a += t[(size_t)csr[i] * 64 + lane];
    acc[(size_t)wid * 64 + lane] = a;
}

// ---------------------------------------------------------------------------
// k_gather32: wave per node, 2 edges/iter (lane>>5 picks edge), shfl combine
// ---------------------------------------------------------------------------
__launch_bounds__(256)
__global__ void k_gather32(const int* __restrict__ ro, const int* __restrict__ csr,
                           const float* __restrict__ t, float* __restrict__ acc)
{
    const int wid = (blockIdx.x << 2) | (threadIdx.x >> 6);
    if (wid >= N_NODES) return;
    const int lane = threadIdx.x & 63;
    const int half = lane >> 5, f = lane & 31;
    const int s = ro[wid], e = ro[wid + 1];
    float a = 0.f;
    int i = s;
    for (; i + 4 <= e; i += 4) {
        int i0 = i + half, i1 = i + 2 + half;
        int s0 = csr[i0], s1 = csr[i1];
        a += t[(size_t)s0 * 32 + f];
        a += t[(size_t)s1 * 32 + f];
    }
    for (; i < e; i += 2) {
        int idx = i + half;
        if (idx < e) a += t[(size_t)csr[idx] * 32 + f];
    }
    a += __shfl_xor(a, 32, 64);
    if (half == 0) acc[(size_t)wid * 32 + f] += a;
}

// ---------------------------------------------------------------------------
// fallback atomic scatter (used only if ws too small for CSR)
// ---------------------------------------------------------------------------
template <int LOGF>
__launch_bounds__(256)
__global__ void k_scatter(const int* __restrict__ ei, const float* __restrict__ t,
                          float* __restrict__ acc)
{
    const int total = N_EDGES << LOGF;
    const int stride = gridDim.x * 256;
    for (int i = blockIdx.x * 256 + threadIdx.x; i < total; i += stride) {
        const int e = i >> LOGF;
        const int f = i & ((1 << LOGF) - 1);
        const int src = ei[e];
        const int dst = ei[N_EDGES + e];
        atomicAdd(acc + ((size_t)dst << LOGF) + f, t[((size_t)src << LOGF) + f]);
    }
}

// ---------------------------------------------------------------------------
// k_pos: out = lrelu(acc2) @ pos_w.T + pos_b
// ---------------------------------------------------------------------------
__launch_bounds__(256)
__global__ void k_pos(const float* __restrict__ acc2, const float* __restrict__ PW,
                      const float* __restrict__ PB, float* __restrict__ out)
{
    const int n = blockIdx.x * 256 + threadIdx.x;
    if (n >= N_NODES) return;
    float h[32];
    const float4* rp = (const float4*)(acc2 + (size_t)n * 32);
#pragma unroll
    for (int i = 0; i < 8; i++) {
        float4 v = rp[i];
        h[4 * i + 0] = lrelu(v.x);
        h[4 * i + 1] = lrelu(v.y);
        h[4 * i + 2] = lrelu(v.z);
        h[4 * i + 3] = lrelu(v.w);
    }
#pragma unroll
    for (int c = 0; c < 3; c++) {
        float s = PB[c];
#pragma unroll
        for (int k = 0; k < 32; k++) s += h[k] * PW[c * 32 + k];
        out[(size_t)n * 3 + c] = s;
    }
}

// ---------------------------------------------------------------------------
extern "C" void kernel_launch(void* const* d_in, const int* in_sizes, int n_in,
                              void* d_out, int out_size, void* d_ws, size_t ws_size,
                              hipStream_t stream)
{
    const float* x        = (const float*)d_in[0];
    const int*   ei       = (const int*)d_in[1];
    const float* lin1_w   = (const float*)d_in[2];
    const float* lin1_b   = (const float*)d_in[3];
    const float* c1_wrel  = (const float*)d_in[4];
    const float* c1_brel  = (const float*)d_in[5];
    const float* c1_wroot = (const float*)d_in[6];
    const float* c4_wrel  = (const float*)d_in[7];
    const float* c4_brel  = (const float*)d_in[8];
    const float* c4_wroot = (const float*)d_in[9];
    const float* pos_w    = (const float*)d_in[10];
    const float* pos_b    = (const float*)d_in[11];
    float* out = (float*)d_out;

    float* h1   = (float*)d_ws;                    // 50000*128
    float* t1   = h1   + (size_t)N_NODES * 128;    // 50000*64
    float* acc1 = t1   + (size_t)N_NODES * 64;     // 50000*64
    float* t2   = acc1 + (size_t)N_NODES * 64;     // 50000*32
    float* acc2 = t2   + (size_t)N_NODES * 32;     // 50000*32
    // int region after the 64 MB of floats
    int* ibase = (int*)(acc2 + (size_t)N_NODES * 32);
    const int NPAD = ((N_NODES + 255) / 256) * 256;  // 50176
    int* deg  = ibase;              // NPAD
    int* tmp  = deg  + NPAD;        // NPAD
    int* ro   = tmp  + NPAD;        // N_NODES+1 (pad to NPAD)
    int* cur  = ro   + NPAD;        // NPAD
    int* bsum = cur  + NPAD;        // 256
    int* boff = bsum + 256;         // 256
    int* csr  = boff + 256;         // N_EDGES

    const size_t needed = ((size_t)N_NODES * (128 + 64 + 64 + 32 + 32)) * 4
                        + ((size_t)NPAD * 4 + 512 + N_EDGES) * 4;
    const bool use_csr = ws_size >= needed;
    const int NB = (N_NODES + 255) / 256;  // 196

    // 1) h1 = lrelu(x @ lin1_w.T + b)
    hipLaunchKernelGGL(k_lin1, dim3((N_NODES + 63) / 64), dim3(256), 0, stream,
                       x, lin1_w, lin1_b, h1);

    if (use_csr) {
        // CSR build (independent of lin1/dual; serialized on stream)
        hipLaunchKernelGGL(k_zero, dim3(NB), dim3(256), 0, stream, deg, N_NODES);
        hipLaunchKernelGGL(k_hist, dim3(2048), dim3(256), 0, stream, ei, deg);
        hipLaunchKernelGGL(k_scan1, dim3(NB), dim3(256), 0, stream, deg, tmp, bsum);
        hipLaunchKernelGGL(k_scan2, dim3(1), dim3(64), 0, stream, bsum, boff, NB);
        hipLaunchKernelGGL(k_scan3, dim3(NB), dim3(256), 0, stream, tmp, boff, deg, ro, cur);
        hipLaunchKernelGGL(k_fill, dim3(2048), dim3(256), 0, stream, ei, cur, csr);
    }

    // 2) t1 = h1 @ c1_wrel.T ; acc1 = h1 @ c1_wroot.T + b_rel
    hipLaunchKernelGGL((k_dual<128, 64, false>), dim3(768), dim3(256), 0, stream,
                       h1, c1_wrel, c1_wroot, c1_brel, t1, acc1);
    // 3) acc1[n] += sum_{e: dst=n} t1[src]
    if (use_csr)
        hipLaunchKernelGGL(k_gather64, dim3((N_NODES + 3) / 4), dim3(256), 0, stream,
                           ro, csr, t1, acc1);
    else
        hipLaunchKernelGGL((k_scatter<6>), dim3(32768), dim3(256), 0, stream, ei, t1, acc1);
    // 4) t2 / acc2
    hipLaunchKernelGGL((k_dual<64, 32, true>), dim3(768), dim3(256), 0, stream,
                       acc1, c4_wrel, c4_wroot, c4_brel, t2, acc2);
    // 5) acc2[n] += sum t2[src]
    if (use_csr)
        hipLaunchKernelGGL(k_gather32, dim3((N_NODES + 3) / 4), dim3(256), 0, stream,
                           ro, csr, t2, acc2);
    else
        hipLaunchKernelGGL((k_scatter<5>), dim3(16384), dim3(256), 0, stream, ei, t2, acc2);
    // 6) out
    hipLaunchKernelGGL(k_pos, dim3((N_NODES + 255) / 256), dim3(256), 0, stream,
                       acc2, pos_w, pos_b, out);
}

// Round 3
// 605.556 us; speedup vs baseline: 1.4839x; 1.1790x over previous
//
#include <hip/hip_runtime.h>

#define N_NODES 50000
#define N_EDGES 1600000

typedef __attribute__((ext_vector_type(4))) float f32x4;
typedef __attribute__((ext_vector_type(8))) short bf16x8;
typedef unsigned short u16;

__device__ __forceinline__ float lrelu(float x) { return x >= 0.f ? x : 0.01f * x; }

// f32 -> bf16 round-to-nearest-even
__device__ __forceinline__ u16 f2bf(float f) {
    union { float f; unsigned u; } v; v.f = f;
    unsigned u = v.u;
    u += 0x7fffu + ((u >> 16) & 1u);
    return (u16)(u >> 16);
}

__device__ __forceinline__ bf16x8 cvt8(float4 a, float4 b) {
    bf16x8 r;
    r[0] = (short)f2bf(a.x); r[1] = (short)f2bf(a.y);
    r[2] = (short)f2bf(a.z); r[3] = (short)f2bf(a.w);
    r[4] = (short)f2bf(b.x); r[5] = (short)f2bf(b.y);
    r[6] = (short)f2bf(b.z); r[7] = (short)f2bf(b.w);
    return r;
}

// ---------------------------------------------------------------------------
// Weight prep: fragment-ordered bf16 tables Wf[kstep][nf][lane][8]
// element (ks,nf,lane,e) = W[nf*16 + (lane&15)][ks*32 + 8*(lane>>4) + e]
// ---------------------------------------------------------------------------
__launch_bounds__(256)
__global__ void k_wprep1(const float* __restrict__ W, u16* __restrict__ Wf)
{   // lin1_w [128][2048] -> 64 ksteps x 8 nf : 262144 elems
    int i = blockIdx.x * 256 + threadIdx.x;
    int e = i & 7, lane = (i >> 3) & 63, nf = (i >> 9) & 7, ks = i >> 12;
    int n = nf * 16 + (lane & 15);
    int k = ks * 32 + 8 * (lane >> 4) + e;
    Wf[i] = f2bf(W[(size_t)n * 2048 + k]);
}

__launch_bounds__(256)
__global__ void k_wprep2(const float* __restrict__ Wrel, const float* __restrict__ Wroot,
                         u16* __restrict__ Wf)
{   // concat([c1_wrel;c1_wroot]) [128][128] -> 4 ksteps x 8 nf : 16384 elems
    int i = blockIdx.x * 256 + threadIdx.x;
    int e = i & 7, lane = (i >> 3) & 63, nf = (i >> 9) & 7, ks = i >> 12;
    int n = nf * 16 + (lane & 15);
    int k = ks * 32 + 8 * (lane >> 4) + e;
    float v = (n < 64) ? Wrel[(size_t)n * 128 + k] : Wroot[(size_t)(n - 64) * 128 + k];
    Wf[i] = f2bf(v);
}

__launch_bounds__(256)
__global__ void k_wprep3(const float* __restrict__ Wrel, const float* __restrict__ Wroot,
                         u16* __restrict__ Wf)
{   // concat([c4_wrel;c4_wroot]) [64][64] -> 2 ksteps x 4 nf : 4096 elems
    int i = blockIdx.x * 256 + threadIdx.x;
    int e = i & 7, lane = (i >> 3) & 63, nf = (i >> 9) & 3, ks = i >> 11;
    int n = nf * 16 + (lane & 15);
    int k = ks * 32 + 8 * (lane >> 4) + e;
    float v = (n < 32) ? Wrel[(size_t)n * 64 + k] : Wroot[(size_t)(n - 32) * 64 + k];
    Wf[i] = f2bf(v);
}

// ---------------------------------------------------------------------------
// k_lin1f: h1(bf16) = lrelu(x @ lin1_w.T + b). Barrier-free, LDS-free.
// Wave owns 16 rows; A-frag direct from global (f32->bf16 in regs);
// B-frags stream from fragment-ordered Wf (perfect 16B/lane coalescing).
// ---------------------------------------------------------------------------
__launch_bounds__(256)
__global__ void k_lin1f(const float* __restrict__ X, const u16* __restrict__ Wf,
                        const float* __restrict__ Bv, u16* __restrict__ H)
{
    const int t = threadIdx.x, wave = t >> 6, lane = t & 63;
    const int lrow = lane & 15, lgrp = lane >> 4;
    const int arow = blockIdx.x * 64 + wave * 16 + lrow;
    const float* ap = X + (size_t)(arow < N_NODES ? arow : 0) * 2048 + 8 * lgrp;
    const u16* bp = Wf + lane * 8;

    f32x4 acc[8];
#pragma unroll
    for (int i = 0; i < 8; i++) acc[i] = (f32x4)0.f;

#pragma unroll 2
    for (int ks = 0; ks < 64; ks++) {
        float4 a0 = *(const float4*)(ap);
        float4 a1 = *(const float4*)(ap + 4);
        bf16x8 af = cvt8(a0, a1);
        const u16* b = bp + ks * 4096;
#pragma unroll
        for (int nf = 0; nf < 8; nf++) {
            bf16x8 bf = *(const bf16x8*)(b + nf * 512);
            acc[nf] = __builtin_amdgcn_mfma_f32_16x16x32_bf16(af, bf, acc[nf], 0, 0, 0);
        }
        ap += 32;
    }

    const int rbase = blockIdx.x * 64 + wave * 16 + lgrp * 4;
#pragma unroll
    for (int nf = 0; nf < 8; nf++) {
        const int col = nf * 16 + lrow;
        const float bias = Bv[col];
#pragma unroll
        for (int r = 0; r < 4; r++) {
            const int row = rbase + r;
            if (row < N_NODES)
                H[(size_t)row * 128 + col] = f2bf(lrelu(acc[nf][r] + bias));
        }
    }
}

// ---------------------------------------------------------------------------
// k_dualf1: t1 = h1 @ c1_wrel.T ; acc1 = h1 @ c1_wroot.T + b_rel  (MFMA, K=128)
// A-frags load bf16 h1 directly (no conversion).
// ---------------------------------------------------------------------------
__launch_bounds__(256)
__global__ void k_dualf1(const u16* __restrict__ Hb, const u16* __restrict__ Wf,
                         const float* __restrict__ brel,
                         float* __restrict__ t1, float* __restrict__ acc1)
{
    const int t = threadIdx.x, wave = t >> 6, lane = t & 63;
    const int lrow = lane & 15, lgrp = lane >> 4;
    const int arow = blockIdx.x * 64 + wave * 16 + lrow;
    const u16* ap = Hb + (size_t)(arow < N_NODES ? arow : 0) * 128 + 8 * lgrp;
    const u16* bp = Wf + lane * 8;

    f32x4 acc[8];
#pragma unroll
    for (int i = 0; i < 8; i++) acc[i] = (f32x4)0.f;

#pragma unroll
    for (int ks = 0; ks < 4; ks++) {
        bf16x8 af = *(const bf16x8*)(ap + ks * 32);
#pragma unroll
        for (int nf = 0; nf < 8; nf++) {
            bf16x8 bf = *(const bf16x8*)(bp + ks * 4096 + nf * 512);
            acc[nf] = __builtin_amdgcn_mfma_f32_16x16x32_bf16(af, bf, acc[nf], 0, 0, 0);
        }
    }

    const int rbase = blockIdx.x * 64 + wave * 16 + lgrp * 4;
#pragma unroll
    for (int nf = 0; nf < 8; nf++) {
        const int col = nf * 16 + lrow;
#pragma unroll
        for (int r = 0; r < 4; r++) {
            const int row = rbase + r;
            if (row < N_NODES) {
                if (col < 64) t1[(size_t)row * 64 + col] = acc[nf][r];
                else          acc1[(size_t)row * 64 + (col - 64)] = acc[nf][r] + brel[col - 64];
            }
        }
    }
}

// ---------------------------------------------------------------------------
// k_dualf2: t2 = lrelu(acc1) @ c4_wrel.T ; acc2 = lrelu(acc1) @ c4_wroot.T + b
// (MFMA, K=64, N=64). A from f32 acc1 with lrelu+cvt in regs.
// ---------------------------------------------------------------------------
__launch_bounds__(256)
__global__ void k_dualf2(const float* __restrict__ A, const u16* __restrict__ Wf,
                         const float* __restrict__ brel,
                         float* __restrict__ t2, float* __restrict__ acc2)
{
    const int t = threadIdx.x, wave = t >> 6, lane = t & 63;
    const int lrow = lane & 15, lgrp = lane >> 4;
    const int arow = blockIdx.x * 64 + wave * 16 + lrow;
    const float* ap = A + (size_t)(arow < N_NODES ? arow : 0) * 64 + 8 * lgrp;
    const u16* bp = Wf + lane * 8;

    f32x4 acc[4];
#pragma unroll
    for (int i = 0; i < 4; i++) acc[i] = (f32x4)0.f;

#pragma unroll
    for (int ks = 0; ks < 2; ks++) {
        float4 a0 = *(const float4*)(ap + ks * 32);
        float4 a1 = *(const float4*)(ap + ks * 32 + 4);
        a0.x = lrelu(a0.x); a0.y = lrelu(a0.y); a0.z = lrelu(a0.z); a0.w = lrelu(a0.w);
        a1.x = lrelu(a1.x); a1.y = lrelu(a1.y); a1.z = lrelu(a1.z); a1.w = lrelu(a1.w);
        bf16x8 af = cvt8(a0, a1);
#pragma unroll
        for (int nf = 0; nf < 4; nf++) {
            bf16x8 bf = *(const bf16x8*)(bp + ks * 2048 + nf * 512);
            acc[nf] = __builtin_amdgcn_mfma_f32_16x16x32_bf16(af, bf, acc[nf], 0, 0, 0);
        }
    }

    const int rbase = blockIdx.x * 64 + wave * 16 + lgrp * 4;
#pragma unroll
    for (int nf = 0; nf < 4; nf++) {
        const int col = nf * 16 + lrow;
#pragma unroll
        for (int r = 0; r < 4; r++) {
            const int row = rbase + r;
            if (row < N_NODES) {
                if (col < 32) t2[(size_t)row * 32 + col] = acc[nf][r];
                else          acc2[(size_t)row * 32 + (col - 32)] = acc[nf][r] + brel[col - 32];
            }
        }
    }
}

// ---------------------------------------------------------------------------
// CSR build: zero -> hist -> scan1 -> scan2p (parallel) -> scan3 -> fill
// ---------------------------------------------------------------------------
__launch_bounds__(256)
__global__ void k_zero(int* __restrict__ p, int n)
{
    int i = blockIdx.x * 256 + threadIdx.x;
    if (i < n) p[i] = 0;
}

__launch_bounds__(256)
__global__ void k_hist(const int* __restrict__ ei, int* __restrict__ deg)
{
    const int stride = gridDim.x * 256;
    for (int e = blockIdx.x * 256 + threadIdx.x; e < N_EDGES; e += stride)
        atomicAdd(deg + ei[N_EDGES + e], 1);
}

__launch_bounds__(256)
__global__ void k_scan1(const int* __restrict__ deg, int* __restrict__ tmp,
                        int* __restrict__ bsum)
{
    __shared__ int sm[256];
    const int tid = threadIdx.x;
    const int i = blockIdx.x * 256 + tid;
    int d = (i < N_NODES) ? deg[i] : 0;
    sm[tid] = d;
    __syncthreads();
#pragma unroll
    for (int off = 1; off < 256; off <<= 1) {
        int v = (tid >= off) ? sm[tid - off] : 0;
        __syncthreads();
        sm[tid] += v;
        __syncthreads();
    }
    if (i < N_NODES) tmp[i] = sm[tid];
    if (tid == 255) bsum[blockIdx.x] = sm[255];
}

__launch_bounds__(256)
__global__ void k_scan2p(const int* __restrict__ bsum, int* __restrict__ boff, int nb)
{
    __shared__ int sm[256];
    const int tid = threadIdx.x;
    int v = (tid < nb) ? bsum[tid] : 0;
    sm[tid] = v;
    __syncthreads();
#pragma unroll
    for (int off = 1; off < 256; off <<= 1) {
        int u = (tid >= off) ? sm[tid - off] : 0;
        __syncthreads();
        sm[tid] += u;
        __syncthreads();
    }
    if (tid < nb) boff[tid] = sm[tid] - v;  // exclusive
}

__launch_bounds__(256)
__global__ void k_scan3(const int* __restrict__ tmp, const int* __restrict__ boff,
                        const int* __restrict__ deg, int* __restrict__ ro,
                        int* __restrict__ cur)
{
    const int i = blockIdx.x * 256 + threadIdx.x;
    if (i < N_NODES) {
        int incl = tmp[i] + boff[i >> 8];
        ro[i + 1] = incl;
        cur[i] = incl - deg[i];
    }
    if (i == 0) ro[0] = 0;
}

__launch_bounds__(256)
__global__ void k_fill(const int* __restrict__ ei, int* __restrict__ cur,
                       int* __restrict__ csr)
{
    const int stride = gridDim.x * 256;
    for (int e = blockIdx.x * 256 + threadIdx.x; e < N_EDGES; e += stride) {
        const int dst = ei[N_EDGES + e];
        const int p = atomicAdd(cur + dst, 1);
        csr[p] = ei[e];
    }
}

// ---------------------------------------------------------------------------
// gathers (CSR, atomic-free)
// ---------------------------------------------------------------------------
__launch_bounds__(256)
__global__ void k_gather64(const int* __restrict__ ro, const int* __restrict__ csr,
                           const float* __restrict__ t, float* __restrict__ acc)
{
    const int wid = (blockIdx.x << 2) | (threadIdx.x >> 6);
    if (wid >= N_NODES) return;
    const int lane = threadIdx.x & 63;
    const int s = ro[wid], e = ro[wid + 1];
    float a = acc[(size_t)wid * 64 + lane];
    int i = s;
    for (; i + 4 <= e; i += 4) {
        int s0 = csr[i], s1 = csr[i + 1], s2 = csr[i + 2], s3 = csr[i + 3];
        a += t[(size_t)s0 * 64 + lane];
        a += t[(size_t)s1 * 64 + lane];
        a += t[(size_t)s2 * 64 + lane];
        a += t[(size_t)s3 * 64 + lane];
    }
    for (; i < e; ++i) a += t[(size_t)csr[i] * 64 + lane];
    acc[(size_t)wid * 64 + lane] = a;
}

__launch_bounds__(256)
__global__ void k_gather32(const int* __restrict__ ro, const int* __restrict__ csr,
                           const float* __restrict__ t, float* __restrict__ acc)
{
    const int wid = (blockIdx.x << 2) | (threadIdx.x >> 6);
    if (wid >= N_NODES) return;
    const int lane = threadIdx.x & 63;
    const int half = lane >> 5, f = lane & 31;
    const int s = ro[wid], e = ro[wid + 1];
    float a = 0.f;
    int i = s;
    for (; i + 4 <= e; i += 4) {
        int s0 = csr[i + half], s1 = csr[i + 2 + half];
        a += t[(size_t)s0 * 32 + f];
        a += t[(size_t)s1 * 32 + f];
    }
    for (; i < e; i += 2) {
        int idx = i + half;
        if (idx < e) a += t[(size_t)csr[idx] * 32 + f];
    }
    a += __shfl_xor(a, 32, 64);
    if (half == 0) acc[(size_t)wid * 32 + f] += a;
}

// ---------------------------------------------------------------------------
// k_pos: out = lrelu(acc2) @ pos_w.T + pos_b
// ---------------------------------------------------------------------------
__launch_bounds__(256)
__global__ void k_pos(const float* __restrict__ acc2, const float* __restrict__ PW,
                      const float* __restrict__ PB, float* __restrict__ out)
{
    const int n = blockIdx.x * 256 + threadIdx.x;
    if (n >= N_NODES) return;
    float h[32];
    const float4* rp = (const float4*)(acc2 + (size_t)n * 32);
#pragma unroll
    for (int i = 0; i < 8; i++) {
        float4 v = rp[i];
        h[4 * i + 0] = lrelu(v.x);
        h[4 * i + 1] = lrelu(v.y);
        h[4 * i + 2] = lrelu(v.z);
        h[4 * i + 3] = lrelu(v.w);
    }
#pragma unroll
    for (int c = 0; c < 3; c++) {
        float s = PB[c];
#pragma unroll
        for (int k = 0; k < 32; k++) s += h[k] * PW[c * 32 + k];
        out[(size_t)n * 3 + c] = s;
    }
}

// ---------------------------------------------------------------------------
extern "C" void kernel_launch(void* const* d_in, const int* in_sizes, int n_in,
                              void* d_out, int out_size, void* d_ws, size_t ws_size,
                              hipStream_t stream)
{
    const float* x        = (const float*)d_in[0];
    const int*   ei       = (const int*)d_in[1];
    const float* lin1_w   = (const float*)d_in[2];
    const float* lin1_b   = (const float*)d_in[3];
    const float* c1_wrel  = (const float*)d_in[4];
    const float* c1_brel  = (const float*)d_in[5];
    const float* c1_wroot = (const float*)d_in[6];
    const float* c4_wrel  = (const float*)d_in[7];
    const float* c4_brel  = (const float*)d_in[8];
    const float* c4_wroot = (const float*)d_in[9];
    const float* pos_w    = (const float*)d_in[10];
    const float* pos_b    = (const float*)d_in[11];
    float* out = (float*)d_out;

    char* base = (char*)d_ws;
    u16*   h1b  = (u16*)base;                                   // 50000*128 bf16 = 12.8 MB
    float* t1   = (float*)(base + (size_t)12800000);            // 50000*64 f32
    float* acc1 = t1 + (size_t)N_NODES * 64;
    float* t2   = acc1 + (size_t)N_NODES * 64;                  // 50000*32
    float* acc2 = t2 + (size_t)N_NODES * 32;
    u16*   wf1  = (u16*)(acc2 + (size_t)N_NODES * 32);          // 262144
    u16*   wf2  = wf1 + 262144;                                 // 16384
    u16*   wf3  = wf2 + 16384;                                  // 4096
    int*   ibase = (int*)(wf3 + 4096);
    const int NPAD = ((N_NODES + 255) / 256) * 256;             // 50176
    int* deg  = ibase;
    int* tmp  = deg  + NPAD;
    int* ro   = tmp  + NPAD;
    int* cur  = ro   + NPAD;
    int* bsum = cur  + NPAD;
    int* boff = bsum + 256;
    int* csr  = boff + 256;
    const int NB = (N_NODES + 255) / 256;                       // 196

    // weight prep (fragment-ordered bf16 tables)
    hipLaunchKernelGGL(k_wprep1, dim3(1024), dim3(256), 0, stream, lin1_w, wf1);
    hipLaunchKernelGGL(k_wprep2, dim3(64), dim3(256), 0, stream, c1_wrel, c1_wroot, wf2);
    hipLaunchKernelGGL(k_wprep3, dim3(16), dim3(256), 0, stream, c4_wrel, c4_wroot, wf3);

    // CSR build
    hipLaunchKernelGGL(k_zero, dim3(NB), dim3(256), 0, stream, deg, N_NODES);
    hipLaunchKernelGGL(k_hist, dim3(2048), dim3(256), 0, stream, ei, deg);
    hipLaunchKernelGGL(k_scan1, dim3(NB), dim3(256), 0, stream, deg, tmp, bsum);
    hipLaunchKernelGGL(k_scan2p, dim3(1), dim3(256), 0, stream, bsum, boff, NB);
    hipLaunchKernelGGL(k_scan3, dim3(NB), dim3(256), 0, stream, tmp, boff, deg, ro, cur);
    hipLaunchKernelGGL(k_fill, dim3(2048), dim3(256), 0, stream, ei, cur, csr);

    // 1) h1(bf16) = lrelu(x @ lin1_w.T + b)
    hipLaunchKernelGGL(k_lin1f, dim3((N_NODES + 63) / 64), dim3(256), 0, stream,
                       x, wf1, lin1_b, h1b);
    // 2) t1 / acc1
    hipLaunchKernelGGL(k_dualf1, dim3((N_NODES + 63) / 64), dim3(256), 0, stream,
                       h1b, wf2, c1_brel, t1, acc1);
    // 3) acc1 += gather(t1)
    hipLaunchKernelGGL(k_gather64, dim3((N_NODES + 3) / 4), dim3(256), 0, stream,
                       ro, csr, t1, acc1);
    // 4) t2 / acc2
    hipLaunchKernelGGL(k_dualf2, dim3((N_NODES + 63) / 64), dim3(256), 0, stream,
                       acc1, wf3, c4_brel, t2, acc2);
    // 5) acc2 += gather(t2)
    hipLaunchKernelGGL(k_gather32, dim3((N_NODES + 3) / 4), dim3(256), 0, stream,
                       ro, csr, t2, acc2);
    // 6) out
    hipLaunchKernelGGL(k_pos, dim3((N_NODES + 255) / 256), dim3(256), 0, stream,
                       acc2, pos_w, pos_b, out);
}

// Round 4
// 503.757 us; speedup vs baseline: 1.7838x; 1.2021x over previous
//
#include <hip/hip_runtime.h>

#define N_NODES 50000
#define N_EDGES 1600000

typedef __attribute__((ext_vector_type(4))) float f32x4;
typedef __attribute__((ext_vector_type(8))) short bf16x8;
typedef unsigned short u16;

__device__ __forceinline__ float lrelu(float x) { return x >= 0.f ? x : 0.01f * x; }

// f32 -> bf16 round-to-nearest-even
__device__ __forceinline__ u16 f2bf(float f) {
    union { float f; unsigned u; } v; v.f = f;
    unsigned u = v.u;
    u += 0x7fffu + ((u >> 16) & 1u);
    return (u16)(u >> 16);
}

__device__ __forceinline__ bf16x8 cvt8(float4 a, float4 b) {
    bf16x8 r;
    r[0] = (short)f2bf(a.x); r[1] = (short)f2bf(a.y);
    r[2] = (short)f2bf(a.z); r[3] = (short)f2bf(a.w);
    r[4] = (short)f2bf(b.x); r[5] = (short)f2bf(b.y);
    r[6] = (short)f2bf(b.z); r[7] = (short)f2bf(b.w);
    return r;
}

// ---------------------------------------------------------------------------
// Weight prep: fragment-ordered bf16 tables Wf[kstep][nf][lane][8]
// element (ks,nf,lane,e) = W[nf*16 + (lane&15)][ks*32 + 8*(lane>>4) + e]
// ---------------------------------------------------------------------------
__launch_bounds__(256)
__global__ void k_wprep1(const float* __restrict__ W, u16* __restrict__ Wf)
{   // lin1_w [128][2048] -> 64 ksteps x 8 nf
    int i = blockIdx.x * 256 + threadIdx.x;
    int e = i & 7, lane = (i >> 3) & 63, nf = (i >> 9) & 7, ks = i >> 12;
    int n = nf * 16 + (lane & 15);
    int k = ks * 32 + 8 * (lane >> 4) + e;
    Wf[i] = f2bf(W[(size_t)n * 2048 + k]);
}

__launch_bounds__(256)
__global__ void k_wprep2(const float* __restrict__ Wrel, const float* __restrict__ Wroot,
                         u16* __restrict__ Wf)
{   // concat([c1_wrel;c1_wroot]) [128][128] -> 4 ksteps x 8 nf
    int i = blockIdx.x * 256 + threadIdx.x;
    int e = i & 7, lane = (i >> 3) & 63, nf = (i >> 9) & 7, ks = i >> 12;
    int n = nf * 16 + (lane & 15);
    int k = ks * 32 + 8 * (lane >> 4) + e;
    float v = (n < 64) ? Wrel[(size_t)n * 128 + k] : Wroot[(size_t)(n - 64) * 128 + k];
    Wf[i] = f2bf(v);
}

__launch_bounds__(256)
__global__ void k_wprep3(const float* __restrict__ Wrel, const float* __restrict__ Wroot,
                         u16* __restrict__ Wf)
{   // concat([c4_wrel;c4_wroot]) [64][64] -> 2 ksteps x 4 nf
    int i = blockIdx.x * 256 + threadIdx.x;
    int e = i & 7, lane = (i >> 3) & 63, nf = (i >> 9) & 3, ks = i >> 11;
    int n = nf * 16 + (lane & 15);
    int k = ks * 32 + 8 * (lane >> 4) + e;
    float v = (n < 32) ? Wrel[(size_t)n * 64 + k] : Wroot[(size_t)(n - 32) * 64 + k];
    Wf[i] = f2bf(v);
}

// ---------------------------------------------------------------------------
// k_lin1f: h1(bf16) = lrelu(x @ lin1_w.T + b). Barrier-free, LDS-free,
// software-pipelined: A prefetch 2-deep (HBM), B prefetch 1-deep (L2).
// ---------------------------------------------------------------------------
__launch_bounds__(256, 1)
__global__ void k_lin1f(const float* __restrict__ X, const u16* __restrict__ Wf,
                        const float* __restrict__ Bv, u16* __restrict__ H)
{
    const int t = threadIdx.x, wave = t >> 6, lane = t & 63;
    const int lrow = lane & 15, lgrp = lane >> 4;
    const int arow = blockIdx.x * 64 + wave * 16 + lrow;
    const float* ap = X + (size_t)(arow < N_NODES ? arow : 0) * 2048 + 8 * lgrp;
    const u16* bp = Wf + lane * 8;

    f32x4 acc[8];
#pragma unroll
    for (int i = 0; i < 8; i++) acc[i] = (f32x4)0.f;

    // prologue: A for ks=0,1 ; B for ks=0
    float4 a0c = *(const float4*)(ap + 0);
    float4 a1c = *(const float4*)(ap + 4);
    float4 a0n = *(const float4*)(ap + 32);
    float4 a1n = *(const float4*)(ap + 36);
    bf16x8 b0 = *(const bf16x8*)(bp + 0 * 512);
    bf16x8 b1 = *(const bf16x8*)(bp + 1 * 512);
    bf16x8 b2 = *(const bf16x8*)(bp + 2 * 512);
    bf16x8 b3 = *(const bf16x8*)(bp + 3 * 512);
    bf16x8 b4 = *(const bf16x8*)(bp + 4 * 512);
    bf16x8 b5 = *(const bf16x8*)(bp + 5 * 512);
    bf16x8 b6 = *(const bf16x8*)(bp + 6 * 512);
    bf16x8 b7 = *(const bf16x8*)(bp + 7 * 512);

#pragma unroll 2
    for (int ks = 0; ks < 64; ks++) {
        const int ksa = (ks + 2 < 64) ? ks + 2 : 63;   // A prefetch target
        const int ksb = (ks + 1 < 64) ? ks + 1 : 63;   // B prefetch target
        // issue next loads first (stay in flight across the MFMAs)
        float4 na0 = *(const float4*)(ap + ksa * 32);
        float4 na1 = *(const float4*)(ap + ksa * 32 + 4);
        const u16* bn = bp + ksb * 4096;
        bf16x8 nb0 = *(const bf16x8*)(bn + 0 * 512);
        bf16x8 nb1 = *(const bf16x8*)(bn + 1 * 512);
        bf16x8 nb2 = *(const bf16x8*)(bn + 2 * 512);
        bf16x8 nb3 = *(const bf16x8*)(bn + 3 * 512);
        bf16x8 nb4 = *(const bf16x8*)(bn + 4 * 512);
        bf16x8 nb5 = *(const bf16x8*)(bn + 5 * 512);
        bf16x8 nb6 = *(const bf16x8*)(bn + 6 * 512);
        bf16x8 nb7 = *(const bf16x8*)(bn + 7 * 512);

        bf16x8 af = cvt8(a0c, a1c);
        acc[0] = __builtin_amdgcn_mfma_f32_16x16x32_bf16(af, b0, acc[0], 0, 0, 0);
        acc[1] = __builtin_amdgcn_mfma_f32_16x16x32_bf16(af, b1, acc[1], 0, 0, 0);
        acc[2] = __builtin_amdgcn_mfma_f32_16x16x32_bf16(af, b2, acc[2], 0, 0, 0);
        acc[3] = __builtin_amdgcn_mfma_f32_16x16x32_bf16(af, b3, acc[3], 0, 0, 0);
        acc[4] = __builtin_amdgcn_mfma_f32_16x16x32_bf16(af, b4, acc[4], 0, 0, 0);
        acc[5] = __builtin_amdgcn_mfma_f32_16x16x32_bf16(af, b5, acc[5], 0, 0, 0);
        acc[6] = __builtin_amdgcn_mfma_f32_16x16x32_bf16(af, b6, acc[6], 0, 0, 0);
        acc[7] = __builtin_amdgcn_mfma_f32_16x16x32_bf16(af, b7, acc[7], 0, 0, 0);

        a0c = a0n; a1c = a1n; a0n = na0; a1n = na1;
        b0 = nb0; b1 = nb1; b2 = nb2; b3 = nb3;
        b4 = nb4; b5 = nb5; b6 = nb6; b7 = nb7;
    }

    const int rbase = blockIdx.x * 64 + wave * 16 + lgrp * 4;
#pragma unroll
    for (int nf = 0; nf < 8; nf++) {
        const int col = nf * 16 + lrow;
        const float bias = Bv[col];
#pragma unroll
        for (int r = 0; r < 4; r++) {
            const int row = rbase + r;
            if (row < N_NODES)
                H[(size_t)row * 128 + col] = f2bf(lrelu(acc[nf][r] + bias));
        }
    }
}

// ---------------------------------------------------------------------------
// k_dualf1: t1 = h1 @ c1_wrel.T ; acc1 = h1 @ c1_wroot.T + b_rel  (K=128)
// All 4 A-frags upfront (bf16 h1, no conversion); B prefetched 1 step ahead.
// ---------------------------------------------------------------------------
__launch_bounds__(256, 1)
__global__ void k_dualf1(const u16* __restrict__ Hb, const u16* __restrict__ Wf,
                         const float* __restrict__ brel,
                         float* __restrict__ t1, float* __restrict__ acc1)
{
    const int t = threadIdx.x, wave = t >> 6, lane = t & 63;
    const int lrow = lane & 15, lgrp = lane >> 4;
    const int arow = blockIdx.x * 64 + wave * 16 + lrow;
    const u16* ap = Hb + (size_t)(arow < N_NODES ? arow : 0) * 128 + 8 * lgrp;
    const u16* bp = Wf + lane * 8;

    f32x4 acc[8];
#pragma unroll
    for (int i = 0; i < 8; i++) acc[i] = (f32x4)0.f;

    bf16x8 a0 = *(const bf16x8*)(ap + 0);
    bf16x8 a1 = *(const bf16x8*)(ap + 32);
    bf16x8 a2 = *(const bf16x8*)(ap + 64);
    bf16x8 a3 = *(const bf16x8*)(ap + 96);
    bf16x8 af[4] = {a0, a1, a2, a3};

    bf16x8 b0 = *(const bf16x8*)(bp + 0 * 512);
    bf16x8 b1 = *(const bf16x8*)(bp + 1 * 512);
    bf16x8 b2 = *(const bf16x8*)(bp + 2 * 512);
    bf16x8 b3 = *(const bf16x8*)(bp + 3 * 512);
    bf16x8 b4 = *(const bf16x8*)(bp + 4 * 512);
    bf16x8 b5 = *(const bf16x8*)(bp + 5 * 512);
    bf16x8 b6 = *(const bf16x8*)(bp + 6 * 512);
    bf16x8 b7 = *(const bf16x8*)(bp + 7 * 512);

#pragma unroll
    for (int ks = 0; ks < 4; ks++) {
        const int ksb = (ks + 1 < 4) ? ks + 1 : 3;
        const u16* bn = bp + ksb * 4096;
        bf16x8 nb0 = *(const bf16x8*)(bn + 0 * 512);
        bf16x8 nb1 = *(const bf16x8*)(bn + 1 * 512);
        bf16x8 nb2 = *(const bf16x8*)(bn + 2 * 512);
        bf16x8 nb3 = *(const bf16x8*)(bn + 3 * 512);
        bf16x8 nb4 = *(const bf16x8*)(bn + 4 * 512);
        bf16x8 nb5 = *(const bf16x8*)(bn + 5 * 512);
        bf16x8 nb6 = *(const bf16x8*)(bn + 6 * 512);
        bf16x8 nb7 = *(const bf16x8*)(bn + 7 * 512);

        bf16x8 a = af[ks];
        acc[0] = __builtin_amdgcn_mfma_f32_16x16x32_bf16(a, b0, acc[0], 0, 0, 0);
        acc[1] = __builtin_amdgcn_mfma_f32_16x16x32_bf16(a, b1, acc[1], 0, 0, 0);
        acc[2] = __builtin_amdgcn_mfma_f32_16x16x32_bf16(a, b2, acc[2], 0, 0, 0);
        acc[3] = __builtin_amdgcn_mfma_f32_16x16x32_bf16(a, b3, acc[3], 0, 0, 0);
        acc[4] = __builtin_amdgcn_mfma_f32_16x16x32_bf16(a, b4, acc[4], 0, 0, 0);
        acc[5] = __builtin_amdgcn_mfma_f32_16x16x32_bf16(a, b5, acc[5], 0, 0, 0);
        acc[6] = __builtin_amdgcn_mfma_f32_16x16x32_bf16(a, b6, acc[6], 0, 0, 0);
        acc[7] = __builtin_amdgcn_mfma_f32_16x16x32_bf16(a, b7, acc[7], 0, 0, 0);

        b0 = nb0; b1 = nb1; b2 = nb2; b3 = nb3;
        b4 = nb4; b5 = nb5; b6 = nb6; b7 = nb7;
    }

    const int rbase = blockIdx.x * 64 + wave * 16 + lgrp * 4;
#pragma unroll
    for (int nf = 0; nf < 8; nf++) {
        const int col = nf * 16 + lrow;
#pragma unroll
        for (int r = 0; r < 4; r++) {
            const int row = rbase + r;
            if (row < N_NODES) {
                if (col < 64) t1[(size_t)row * 64 + col] = acc[nf][r];
                else          acc1[(size_t)row * 64 + (col - 64)] = acc[nf][r] + brel[col - 64];
            }
        }
    }
}

// ---------------------------------------------------------------------------
// k_dualf2: t2/acc2 from lrelu(acc1)  (K=64, N=64) — fully unrolled, all
// loads issued upfront.
// ---------------------------------------------------------------------------
__launch_bounds__(256, 1)
__global__ void k_dualf2(const float* __restrict__ A, const u16* __restrict__ Wf,
                         const float* __restrict__ brel,
                         float* __restrict__ t2, float* __restrict__ acc2)
{
    const int t = threadIdx.x, wave = t >> 6, lane = t & 63;
    const int lrow = lane & 15, lgrp = lane >> 4;
    const int arow = blockIdx.x * 64 + wave * 16 + lrow;
    const float* ap = A + (size_t)(arow < N_NODES ? arow : 0) * 64 + 8 * lgrp;
    const u16* bp = Wf + lane * 8;

    float4 a00 = *(const float4*)(ap + 0);
    float4 a01 = *(const float4*)(ap + 4);
    float4 a10 = *(const float4*)(ap + 32);
    float4 a11 = *(const float4*)(ap + 36);
    bf16x8 b00 = *(const bf16x8*)(bp + 0 * 512);
    bf16x8 b01 = *(const bf16x8*)(bp + 1 * 512);
    bf16x8 b02 = *(const bf16x8*)(bp + 2 * 512);
    bf16x8 b03 = *(const bf16x8*)(bp + 3 * 512);
    bf16x8 b10 = *(const bf16x8*)(bp + 2048 + 0 * 512);
    bf16x8 b11 = *(const bf16x8*)(bp + 2048 + 1 * 512);
    bf16x8 b12 = *(const bf16x8*)(bp + 2048 + 2 * 512);
    bf16x8 b13 = *(const bf16x8*)(bp + 2048 + 3 * 512);

    f32x4 acc[4];
#pragma unroll
    for (int i = 0; i < 4; i++) acc[i] = (f32x4)0.f;

    a00.x = lrelu(a00.x); a00.y = lrelu(a00.y); a00.z = lrelu(a00.z); a00.w = lrelu(a00.w);
    a01.x = lrelu(a01.x); a01.y = lrelu(a01.y); a01.z = lrelu(a01.z); a01.w = lrelu(a01.w);
    bf16x8 af0 = cvt8(a00, a01);
    acc[0] = __builtin_amdgcn_mfma_f32_16x16x32_bf16(af0, b00, acc[0], 0, 0, 0);
    acc[1] = __builtin_amdgcn_mfma_f32_16x16x32_bf16(af0, b01, acc[1], 0, 0, 0);
    acc[2] = __builtin_amdgcn_mfma_f32_16x16x32_bf16(af0, b02, acc[2], 0, 0, 0);
    acc[3] = __builtin_amdgcn_mfma_f32_16x16x32_bf16(af0, b03, acc[3], 0, 0, 0);

    a10.x = lrelu(a10.x); a10.y = lrelu(a10.y); a10.z = lrelu(a10.z); a10.w = lrelu(a10.w);
    a11.x = lrelu(a11.x); a11.y = lrelu(a11.y); a11.z = lrelu(a11.z); a11.w = lrelu(a11.w);
    bf16x8 af1 = cvt8(a10, a11);
    acc[0] = __builtin_amdgcn_mfma_f32_16x16x32_bf16(af1, b10, acc[0], 0, 0, 0);
    acc[1] = __builtin_amdgcn_mfma_f32_16x16x32_bf16(af1, b11, acc[1], 0, 0, 0);
    acc[2] = __builtin_amdgcn_mfma_f32_16x16x32_bf16(af1, b12, acc[2], 0, 0, 0);
    acc[3] = __builtin_amdgcn_mfma_f32_16x16x32_bf16(af1, b13, acc[3], 0, 0, 0);

    const int rbase = blockIdx.x * 64 + wave * 16 + lgrp * 4;
#pragma unroll
    for (int nf = 0; nf < 4; nf++) {
        const int col = nf * 16 + lrow;
#pragma unroll
        for (int r = 0; r < 4; r++) {
            const int row = rbase + r;
            if (row < N_NODES) {
                if (col < 32) t2[(size_t)row * 32 + col] = acc[nf][r];
                else          acc2[(size_t)row * 32 + (col - 32)] = acc[nf][r] + brel[col - 32];
            }
        }
    }
}

// ---------------------------------------------------------------------------
// CSR build: zero -> hist -> scan1 -> scan2p -> scan3 -> fill
// ---------------------------------------------------------------------------
__launch_bounds__(256)
__global__ void k_zero(int* __restrict__ p, int n)
{
    int i = blockIdx.x * 256 + threadIdx.x;
    if (i < n) p[i] = 0;
}

__launch_bounds__(256)
__global__ void k_hist(const int* __restrict__ ei, int* __restrict__ deg)
{
    const int stride = gridDim.x * 256;
    for (int e = blockIdx.x * 256 + threadIdx.x; e < N_EDGES; e += stride)
        atomicAdd(deg + ei[N_EDGES + e], 1);
}

__launch_bounds__(256)
__global__ void k_scan1(const int* __restrict__ deg, int* __restrict__ tmp,
                        int* __restrict__ bsum)
{
    __shared__ int sm[256];
    const int tid = threadIdx.x;
    const int i = blockIdx.x * 256 + tid;
    int d = (i < N_NODES) ? deg[i] : 0;
    sm[tid] = d;
    __syncthreads();
#pragma unroll
    for (int off = 1; off < 256; off <<= 1) {
        int v = (tid >= off) ? sm[tid - off] : 0;
        __syncthreads();
        sm[tid] += v;
        __syncthreads();
    }
    if (i < N_NODES) tmp[i] = sm[tid];
    if (tid == 255) bsum[blockIdx.x] = sm[255];
}

__launch_bounds__(256)
__global__ void k_scan2p(const int* __restrict__ bsum, int* __restrict__ boff, int nb)
{
    __shared__ int sm[256];
    const int tid = threadIdx.x;
    int v = (tid < nb) ? bsum[tid] : 0;
    sm[tid] = v;
    __syncthreads();
#pragma unroll
    for (int off = 1; off < 256; off <<= 1) {
        int u = (tid >= off) ? sm[tid - off] : 0;
        __syncthreads();
        sm[tid] += u;
        __syncthreads();
    }
    if (tid < nb) boff[tid] = sm[tid] - v;  // exclusive
}

__launch_bounds__(256)
__global__ void k_scan3(const int* __restrict__ tmp, const int* __restrict__ boff,
                        const int* __restrict__ deg, int* __restrict__ ro,
                        int* __restrict__ cur)
{
    const int i = blockIdx.x * 256 + threadIdx.x;
    if (i < N_NODES) {
        int incl = tmp[i] + boff[i >> 8];
        ro[i + 1] = incl;
        cur[i] = incl - deg[i];
    }
    if (i == 0) ro[0] = 0;
}

__launch_bounds__(256)
__global__ void k_fill(const int* __restrict__ ei, int* __restrict__ cur,
                       int* __restrict__ csr)
{
    const int stride = gridDim.x * 256;
    for (int e = blockIdx.x * 256 + threadIdx.x; e < N_EDGES; e += stride) {
        const int dst = ei[N_EDGES + e];
        const int p = atomicAdd(cur + dst, 1);
        csr[p] = ei[e];
    }
}

// ---------------------------------------------------------------------------
// gathers (CSR, atomic-free)
// ---------------------------------------------------------------------------
__launch_bounds__(256)
__global__ void k_gather64(const int* __restrict__ ro, const int* __restrict__ csr,
                           const float* __restrict__ t, float* __restrict__ acc)
{
    const int wid = (blockIdx.x << 2) | (threadIdx.x >> 6);
    if (wid >= N_NODES) return;
    const int lane = threadIdx.x & 63;
    const int s = ro[wid], e = ro[wid + 1];
    float a = acc[(size_t)wid * 64 + lane];
    int i = s;
    for (; i + 4 <= e; i += 4) {
        int s0 = csr[i], s1 = csr[i + 1], s2 = csr[i + 2], s3 = csr[i + 3];
        a += t[(size_t)s0 * 64 + lane];
        a += t[(size_t)s1 * 64 + lane];
        a += t[(size_t)s2 * 64 + lane];
        a += t[(size_t)s3 * 64 + lane];
    }
    for (; i < e; ++i) a += t[(size_t)csr[i] * 64 + lane];
    acc[(size_t)wid * 64 + lane] = a;
}

__launch_bounds__(256)
__global__ void k_gather32(const int* __restrict__ ro, const int* __restrict__ csr,
                           const float* __restrict__ t, float* __restrict__ acc)
{
    const int wid = (blockIdx.x << 2) | (threadIdx.x >> 6);
    if (wid >= N_NODES) return;
    const int lane = threadIdx.x & 63;
    const int half = lane >> 5, f = lane & 31;
    const int s = ro[wid], e = ro[wid + 1];
    float a = 0.f;
    int i = s;
    for (; i + 4 <= e; i += 4) {
        int s0 = csr[i + half], s1 = csr[i + 2 + half];
        a += t[(size_t)s0 * 32 + f];
        a += t[(size_t)s1 * 32 + f];
    }
    for (; i < e; i += 2) {
        int idx = i + half;
        if (idx < e) a += t[(size_t)csr[idx] * 32 + f];
    }
    a += __shfl_xor(a, 32, 64);
    if (half == 0) acc[(size_t)wid * 32 + f] += a;
}

// ---------------------------------------------------------------------------
// k_pos: out = lrelu(acc2) @ pos_w.T + pos_b
// ---------------------------------------------------------------------------
__launch_bounds__(256)
__global__ void k_pos(const float* __restrict__ acc2, const float* __restrict__ PW,
                      const float* __restrict__ PB, float* __restrict__ out)
{
    const int n = blockIdx.x * 256 + threadIdx.x;
    if (n >= N_NODES) return;
    float h[32];
    const float4* rp = (const float4*)(acc2 + (size_t)n * 32);
#pragma unroll
    for (int i = 0; i < 8; i++) {
        float4 v = rp[i];
        h[4 * i + 0] = lrelu(v.x);
        h[4 * i + 1] = lrelu(v.y);
        h[4 * i + 2] = lrelu(v.z);
        h[4 * i + 3] = lrelu(v.w);
    }
#pragma unroll
    for (int c = 0; c < 3; c++) {
        float s = PB[c];
#pragma unroll
        for (int k = 0; k < 32; k++) s += h[k] * PW[c * 32 + k];
        out[(size_t)n * 3 + c] = s;
    }
}

// ---------------------------------------------------------------------------
extern "C" void kernel_launch(void* const* d_in, const int* in_sizes, int n_in,
                              void* d_out, int out_size, void* d_ws, size_t ws_size,
                              hipStream_t stream)
{
    const float* x        = (const float*)d_in[0];
    const int*   ei       = (const int*)d_in[1];
    const float* lin1_w   = (const float*)d_in[2];
    const float* lin1_b   = (const float*)d_in[3];
    const float* c1_wrel  = (const float*)d_in[4];
    const float* c1_brel  = (const float*)d_in[5];
    const float* c1_wroot = (const float*)d_in[6];
    const float* c4_wrel  = (const float*)d_in[7];
    const float* c4_brel  = (const float*)d_in[8];
    const float* c4_wroot = (const float*)d_in[9];
    const float* pos_w    = (const float*)d_in[10];
    const float* pos_b    = (const float*)d_in[11];
    float* out = (float*)d_out;

    char* base = (char*)d_ws;
    u16*   h1b  = (u16*)base;                                   // 50000*128 bf16
    float* t1   = (float*)(base + (size_t)12800000);            // 50000*64 f32
    float* acc1 = t1 + (size_t)N_NODES * 64;
    float* t2   = acc1 + (size_t)N_NODES * 64;                  // 50000*32
    float* acc2 = t2 + (size_t)N_NODES * 32;
    u16*   wf1  = (u16*)(acc2 + (size_t)N_NODES * 32);          // 262144
    u16*   wf2  = wf1 + 262144;                                 // 16384
    u16*   wf3  = wf2 + 16384;                                  // 4096
    int*   ibase = (int*)(wf3 + 4096);
    const int NPAD = ((N_NODES + 255) / 256) * 256;             // 50176
    int* deg  = ibase;
    int* tmp  = deg  + NPAD;
    int* ro   = tmp  + NPAD;
    int* cur  = ro   + NPAD;
    int* bsum = cur  + NPAD;
    int* boff = bsum + 256;
    int* csr  = boff + 256;
    const int NB = (N_NODES + 255) / 256;                       // 196

    // weight prep
    hipLaunchKernelGGL(k_wprep1, dim3(1024), dim3(256), 0, stream, lin1_w, wf1);
    hipLaunchKernelGGL(k_wprep2, dim3(64), dim3(256), 0, stream, c1_wrel, c1_wroot, wf2);
    hipLaunchKernelGGL(k_wprep3, dim3(16), dim3(256), 0, stream, c4_wrel, c4_wroot, wf3);

    // CSR build
    hipLaunchKernelGGL(k_zero, dim3(NB), dim3(256), 0, stream, deg, N_NODES);
    hipLaunchKernelGGL(k_hist, dim3(2048), dim3(256), 0, stream, ei, deg);
    hipLaunchKernelGGL(k_scan1, dim3(NB), dim3(256), 0, stream, deg, tmp, bsum);
    hipLaunchKernelGGL(k_scan2p, dim3(1), dim3(256), 0, stream, bsum, boff, NB);
    hipLaunchKernelGGL(k_scan3, dim3(NB), dim3(256), 0, stream, tmp, boff, deg, ro, cur);
    hipLaunchKernelGGL(k_fill, dim3(2048), dim3(256), 0, stream, ei, cur, csr);

    // 1) h1(bf16) = lrelu(x @ lin1_w.T + b)
    hipLaunchKernelGGL(k_lin1f, dim3((N_NODES + 63) / 64), dim3(256), 0, stream,
                       x, wf1, lin1_b, h1b);
    // 2) t1 / acc1
    hipLaunchKernelGGL(k_dualf1, dim3((N_NODES + 63) / 64), dim3(256), 0, stream,
                       h1b, wf2, c1_brel, t1, acc1);
    // 3) acc1 += gather(t1)
    hipLaunchKernelGGL(k_gather64, dim3((N_NODES + 3) / 4), dim3(256), 0, stream,
                       ro, csr, t1, acc1);
    // 4) t2 / acc2
    hipLaunchKernelGGL(k_dualf2, dim3((N_NODES + 63) / 64), dim3(256), 0, stream,
                       acc1, wf3, c4_brel, t2, acc2);
    // 5) acc2 += gather(t2)
    hipLaunchKernelGGL(k_gather32, dim3((N_NODES + 3) / 4), dim3(256), 0, stream,
                       ro, csr, t2, acc2);
    // 6) out
    hipLaunchKernelGGL(k_pos, dim3((N_NODES + 255) / 256), dim3(256), 0, stream,
                       acc2, pos_w, pos_b, out);
}

// Round 5
// 448.611 us; speedup vs baseline: 2.0031x; 1.1229x over previous
//
#include <hip/hip_runtime.h>

#define N_NODES 50000
#define N_EDGES 1600000

typedef __attribute__((ext_vector_type(4))) float f32x4;
typedef __attribute__((ext_vector_type(8))) short bf16x8;
typedef unsigned short u16;

__device__ __forceinline__ float lrelu(float x) { return x >= 0.f ? x : 0.01f * x; }

// f32 -> bf16 round-to-nearest-even
__device__ __forceinline__ u16 f2bf(float f) {
    union { float f; unsigned u; } v; v.f = f;
    unsigned u = v.u;
    u += 0x7fffu + ((u >> 16) & 1u);
    return (u16)(u >> 16);
}

__device__ __forceinline__ float bf2f(u16 v) {
    union { unsigned u; float f; } x; x.u = ((unsigned)v) << 16; return x.f;
}

__device__ __forceinline__ bf16x8 cvt8(float4 a, float4 b) {
    bf16x8 r;
    r[0] = (short)f2bf(a.x); r[1] = (short)f2bf(a.y);
    r[2] = (short)f2bf(a.z); r[3] = (short)f2bf(a.w);
    r[4] = (short)f2bf(b.x); r[5] = (short)f2bf(b.y);
    r[6] = (short)f2bf(b.z); r[7] = (short)f2bf(b.w);
    return r;
}

// global -> LDS DMA, 16B per lane; lds ptr must be wave-uniform
__device__ __forceinline__ void gload_lds16(const void* g, void* l) {
    __builtin_amdgcn_global_load_lds(
        (const __attribute__((address_space(1))) void*)g,
        (__attribute__((address_space(3))) void*)l, 16, 0, 0);
}

// ---------------------------------------------------------------------------
// Weight prep: fragment-ordered bf16 tables Wf[kstep][nf][lane][8]
// element (ks,nf,lane,e) = W[nf*16 + (lane&15)][ks*32 + 8*(lane>>4) + e]
// ---------------------------------------------------------------------------
__launch_bounds__(256)
__global__ void k_wprep1(const float* __restrict__ W, u16* __restrict__ Wf)
{   // lin1_w [128][2048] -> 64 ksteps x 8 nf
    int i = blockIdx.x * 256 + threadIdx.x;
    int e = i & 7, lane = (i >> 3) & 63, nf = (i >> 9) & 7, ks = i >> 12;
    int n = nf * 16 + (lane & 15);
    int k = ks * 32 + 8 * (lane >> 4) + e;
    Wf[i] = f2bf(W[(size_t)n * 2048 + k]);
}

__launch_bounds__(256)
__global__ void k_wprep2(const float* __restrict__ Wrel, const float* __restrict__ Wroot,
                         u16* __restrict__ Wf)
{   // concat([c1_wrel;c1_wroot]) [128][128] -> 4 ksteps x 8 nf
    int i = blockIdx.x * 256 + threadIdx.x;
    int e = i & 7, lane = (i >> 3) & 63, nf = (i >> 9) & 7, ks = i >> 12;
    int n = nf * 16 + (lane & 15);
    int k = ks * 32 + 8 * (lane >> 4) + e;
    float v = (n < 64) ? Wrel[(size_t)n * 128 + k] : Wroot[(size_t)(n - 64) * 128 + k];
    Wf[i] = f2bf(v);
}

__launch_bounds__(256)
__global__ void k_wprep3(const float* __restrict__ Wrel, const float* __restrict__ Wroot,
                         u16* __restrict__ Wf)
{   // concat([c4_wrel;c4_wroot]) [64][64] -> 2 ksteps x 4 nf
    int i = blockIdx.x * 256 + threadIdx.x;
    int e = i & 7, lane = (i >> 3) & 63, nf = (i >> 9) & 3, ks = i >> 11;
    int n = nf * 16 + (lane & 15);
    int k = ks * 32 + 8 * (lane >> 4) + e;
    float v = (n < 32) ? Wrel[(size_t)n * 64 + k] : Wroot[(size_t)(n - 32) * 64 + k];
    Wf[i] = f2bf(v);
}

// ---------------------------------------------------------------------------
// k_lin1s: h1(bf16) = lrelu(x @ lin1_w.T + b)
// LDS double-buffered, global_load_lds staged (DMA queue holds in-flight
// bytes; ~32KB/block/step => HBM saturated with 2 blocks/CU).
// A tile: [64 rows][64 k] f32, 32B-granule XOR swizzle (byte ^ (row&7)<<5),
//   applied as pre-swizzled SOURCE (linear LDS dest) + swizzled read.
// B tile: 16KB linear slice of the fragment-ordered wf1 table.
// ---------------------------------------------------------------------------
__device__ __forceinline__ void stage_lin1(const float* __restrict__ X,
                                           const u16* __restrict__ Wf,
                                           char* Abuf, char* Bbuf,
                                           int m0, int s, int t)
{
    const int wave = t >> 6;
#pragma unroll
    for (int r = 0; r < 4; r++) {           // A: 16KB
        int row = r * 16 + (t >> 4);
        int grow = m0 + row; if (grow >= N_NODES) grow = 0;
        int bcol = ((t & 15) * 16) ^ ((row & 7) << 5);  // inverse swizzle (involution)
        const float* src = X + (size_t)grow * 2048 + s * 64 + (bcol >> 2);
        gload_lds16(src, Abuf + r * 4096 + wave * 1024);
    }
#pragma unroll
    for (int r = 0; r < 4; r++) {           // B: 16KB linear
        const u16* src = Wf + (size_t)s * 8192 + ((size_t)(r * 256 + t)) * 8;
        gload_lds16(src, Bbuf + r * 4096 + wave * 1024);
    }
}

__launch_bounds__(256, 2)
__global__ void k_lin1s(const float* __restrict__ X, const u16* __restrict__ Wf,
                        const float* __restrict__ Bv, u16* __restrict__ H)
{
    __shared__ __align__(16) char As[2][16384];
    __shared__ __align__(16) char Bs[2][16384];

    const int t = threadIdx.x, wave = t >> 6, lane = t & 63;
    const int lrow = lane & 15, lgrp = lane >> 4;
    const int m0 = blockIdx.x * 64;
    const int myrow = wave * 16 + lrow;

    f32x4 acc[8];
#pragma unroll
    for (int i = 0; i < 8; i++) acc[i] = (f32x4)0.f;

    stage_lin1(X, Wf, As[0], Bs[0], m0, 0, t);
    __syncthreads();

    for (int s = 0; s < 32; s++) {
        const int cur = s & 1;
        if (s < 31) stage_lin1(X, Wf, As[cur ^ 1], Bs[cur ^ 1], m0, s + 1, t);

#pragma unroll
        for (int ksub = 0; ksub < 2; ksub++) {
            const int xr = (ksub * 128 + lgrp * 32) ^ ((myrow & 7) << 5);
            const float4* ar = (const float4*)(As[cur] + myrow * 256 + xr);
            float4 a0 = ar[0], a1 = ar[1];
            bf16x8 af = cvt8(a0, a1);
            const char* bb = Bs[cur] + ksub * 8192 + lane * 16;
#pragma unroll
            for (int nf = 0; nf < 8; nf++) {
                bf16x8 bf = *(const bf16x8*)(bb + nf * 1024);
                acc[nf] = __builtin_amdgcn_mfma_f32_16x16x32_bf16(af, bf, acc[nf], 0, 0, 0);
            }
        }
        __syncthreads();
    }

    const int rbase = m0 + wave * 16 + lgrp * 4;
#pragma unroll
    for (int nf = 0; nf < 8; nf++) {
        const int col = nf * 16 + lrow;
        const float bias = Bv[col];
#pragma unroll
        for (int r = 0; r < 4; r++) {
            const int row = rbase + r;
            if (row < N_NODES)
                H[(size_t)row * 128 + col] = f2bf(lrelu(acc[nf][r] + bias));
        }
    }
}

// ---------------------------------------------------------------------------
// k_dualf1: t1(bf16) = h1 @ c1_wrel.T ; acc1(f32) = h1 @ c1_wroot.T + b_rel
// ---------------------------------------------------------------------------
__launch_bounds__(256, 2)
__global__ void k_dualf1(const u16* __restrict__ Hb, const u16* __restrict__ Wf,
                         const float* __restrict__ brel,
                         u16* __restrict__ t1, float* __restrict__ acc1)
{
    const int t = threadIdx.x, wave = t >> 6, lane = t & 63;
    const int lrow = lane & 15, lgrp = lane >> 4;
    const int arow = blockIdx.x * 64 + wave * 16 + lrow;
    const u16* ap = Hb + (size_t)(arow < N_NODES ? arow : 0) * 128 + 8 * lgrp;
    const u16* bp = Wf + lane * 8;

    f32x4 acc[8];
#pragma unroll
    for (int i = 0; i < 8; i++) acc[i] = (f32x4)0.f;

    bf16x8 a0 = *(const bf16x8*)(ap + 0);
    bf16x8 a1 = *(const bf16x8*)(ap + 32);
    bf16x8 a2 = *(const bf16x8*)(ap + 64);
    bf16x8 a3 = *(const bf16x8*)(ap + 96);
    bf16x8 af[4] = {a0, a1, a2, a3};

#pragma unroll
    for (int ks = 0; ks < 4; ks++) {
        const u16* b = bp + ks * 4096;
        bf16x8 a = af[ks];
#pragma unroll
        for (int nf = 0; nf < 8; nf++) {
            bf16x8 bf = *(const bf16x8*)(b + nf * 512);
            acc[nf] = __builtin_amdgcn_mfma_f32_16x16x32_bf16(a, bf, acc[nf], 0, 0, 0);
        }
    }

    const int rbase = blockIdx.x * 64 + wave * 16 + lgrp * 4;
#pragma unroll
    for (int nf = 0; nf < 8; nf++) {
        const int col = nf * 16 + lrow;
#pragma unroll
        for (int r = 0; r < 4; r++) {
            const int row = rbase + r;
            if (row < N_NODES) {
                if (col < 64) t1[(size_t)row * 64 + col] = f2bf(acc[nf][r]);
                else          acc1[(size_t)row * 64 + (col - 64)] = acc[nf][r] + brel[col - 64];
            }
        }
    }
}

// ---------------------------------------------------------------------------
// k_dualf2: t2(bf16)/acc2(f32) from lrelu(acc1)  (K=64, N=64)
// ---------------------------------------------------------------------------
__launch_bounds__(256, 2)
__global__ void k_dualf2(const float* __restrict__ A, const u16* __restrict__ Wf,
                         const float* __restrict__ brel,
                         u16* __restrict__ t2, float* __restrict__ acc2)
{
    const int t = threadIdx.x, wave = t >> 6, lane = t & 63;
    const int lrow = lane & 15, lgrp = lane >> 4;
    const int arow = blockIdx.x * 64 + wave * 16 + lrow;
    const float* ap = A + (size_t)(arow < N_NODES ? arow : 0) * 64 + 8 * lgrp;
    const u16* bp = Wf + lane * 8;

    float4 a00 = *(const float4*)(ap + 0);
    float4 a01 = *(const float4*)(ap + 4);
    float4 a10 = *(const float4*)(ap + 32);
    float4 a11 = *(const float4*)(ap + 36);

    f32x4 acc[4];
#pragma unroll
    for (int i = 0; i < 4; i++) acc[i] = (f32x4)0.f;

    a00.x = lrelu(a00.x); a00.y = lrelu(a00.y); a00.z = lrelu(a00.z); a00.w = lrelu(a00.w);
    a01.x = lrelu(a01.x); a01.y = lrelu(a01.y); a01.z = lrelu(a01.z); a01.w = lrelu(a01.w);
    bf16x8 af0 = cvt8(a00, a01);
    a10.x = lrelu(a10.x); a10.y = lrelu(a10.y); a10.z = lrelu(a10.z); a10.w = lrelu(a10.w);
    a11.x = lrelu(a11.x); a11.y = lrelu(a11.y); a11.z = lrelu(a11.z); a11.w = lrelu(a11.w);
    bf16x8 af1 = cvt8(a10, a11);

#pragma unroll
    for (int nf = 0; nf < 4; nf++) {
        bf16x8 b0 = *(const bf16x8*)(bp + nf * 512);
        bf16x8 b1 = *(const bf16x8*)(bp + 2048 + nf * 512);
        acc[nf] = __builtin_amdgcn_mfma_f32_16x16x32_bf16(af0, b0, acc[nf], 0, 0, 0);
        acc[nf] = __builtin_amdgcn_mfma_f32_16x16x32_bf16(af1, b1, acc[nf], 0, 0, 0);
    }

    const int rbase = blockIdx.x * 64 + wave * 16 + lgrp * 4;
#pragma unroll
    for (int nf = 0; nf < 4; nf++) {
        const int col = nf * 16 + lrow;
#pragma unroll
        for (int r = 0; r < 4; r++) {
            const int row = rbase + r;
            if (row < N_NODES) {
                if (col < 32) t2[(size_t)row * 32 + col] = f2bf(acc[nf][r]);
                else          acc2[(size_t)row * 32 + (col - 32)] = acc[nf][r] + brel[col - 32];
            }
        }
    }
}

// ---------------------------------------------------------------------------
// CSR build: zero -> hist -> scan1 -> scan2p -> scan3 -> fill
// ---------------------------------------------------------------------------
__launch_bounds__(256)
__global__ void k_zero(int* __restrict__ p, int n)
{
    int i = blockIdx.x * 256 + threadIdx.x;
    if (i < n) p[i] = 0;
}

__launch_bounds__(256)
__global__ void k_hist(const int* __restrict__ ei, int* __restrict__ deg)
{
    const int stride = gridDim.x * 256;
    for (int e = blockIdx.x * 256 + threadIdx.x; e < N_EDGES; e += stride)
        atomicAdd(deg + ei[N_EDGES + e], 1);
}

__launch_bounds__(256)
__global__ void k_scan1(const int* __restrict__ deg, int* __restrict__ tmp,
                        int* __restrict__ bsum)
{
    __shared__ int sm[256];
    const int tid = threadIdx.x;
    const int i = blockIdx.x * 256 + tid;
    int d = (i < N_NODES) ? deg[i] : 0;
    sm[tid] = d;
    __syncthreads();
#pragma unroll
    for (int off = 1; off < 256; off <<= 1) {
        int v = (tid >= off) ? sm[tid - off] : 0;
        __syncthreads();
        sm[tid] += v;
        __syncthreads();
    }
    if (i < N_NODES) tmp[i] = sm[tid];
    if (tid == 255) bsum[blockIdx.x] = sm[255];
}

__launch_bounds__(256)
__global__ void k_scan2p(const int* __restrict__ bsum, int* __restrict__ boff, int nb)
{
    __shared__ int sm[256];
    const int tid = threadIdx.x;
    int v = (tid < nb) ? bsum[tid] : 0;
    sm[tid] = v;
    __syncthreads();
#pragma unroll
    for (int off = 1; off < 256; off <<= 1) {
        int u = (tid >= off) ? sm[tid - off] : 0;
        __syncthreads();
        sm[tid] += u;
        __syncthreads();
    }
    if (tid < nb) boff[tid] = sm[tid] - v;  // exclusive
}

__launch_bounds__(256)
__global__ void k_scan3(const int* __restrict__ tmp, const int* __restrict__ boff,
                        const int* __restrict__ deg, int* __restrict__ ro,
                        int* __restrict__ cur)
{
    const int i = blockIdx.x * 256 + threadIdx.x;
    if (i < N_NODES) {
        int incl = tmp[i] + boff[i >> 8];
        ro[i + 1] = incl;
        cur[i] = incl - deg[i];
    }
    if (i == 0) ro[0] = 0;
}

__launch_bounds__(256)
__global__ void k_fill(const int* __restrict__ ei, int* __restrict__ cur,
                       int* __restrict__ csr)
{
    const int stride = gridDim.x * 256;
    for (int e = blockIdx.x * 256 + threadIdx.x; e < N_EDGES; e += stride) {
        const int dst = ei[N_EDGES + e];
        const int p = atomicAdd(cur + dst, 1);
        csr[p] = ei[e];
    }
}

// ---------------------------------------------------------------------------
// k_gather64: acc1[n] += sum over in-edges of t1(bf16)[src]; wave/node
// ---------------------------------------------------------------------------
__launch_bounds__(256)
__global__ void k_gather64(const int* __restrict__ ro, const int* __restrict__ csr,
                           const u16* __restrict__ t, float* __restrict__ acc)
{
    const int wid = (blockIdx.x << 2) | (threadIdx.x >> 6);
    if (wid >= N_NODES) return;
    const int lane = threadIdx.x & 63;
    const int s = ro[wid], e = ro[wid + 1];
    float a = acc[(size_t)wid * 64 + lane];
    int i = s;
    for (; i + 8 <= e; i += 8) {
        int s0 = csr[i], s1 = csr[i + 1], s2 = csr[i + 2], s3 = csr[i + 3];
        int s4 = csr[i + 4], s5 = csr[i + 5], s6 = csr[i + 6], s7 = csr[i + 7];
        u16 v0 = t[(size_t)s0 * 64 + lane], v1 = t[(size_t)s1 * 64 + lane];
        u16 v2 = t[(size_t)s2 * 64 + lane], v3 = t[(size_t)s3 * 64 + lane];
        u16 v4 = t[(size_t)s4 * 64 + lane], v5 = t[(size_t)s5 * 64 + lane];
        u16 v6 = t[(size_t)s6 * 64 + lane], v7 = t[(size_t)s7 * 64 + lane];
        a += bf2f(v0); a += bf2f(v1); a += bf2f(v2); a += bf2f(v3);
        a += bf2f(v4); a += bf2f(v5); a += bf2f(v6); a += bf2f(v7);
    }
    for (; i < e; ++i) a += bf2f(t[(size_t)csr[i] * 64 + lane]);
    acc[(size_t)wid * 64 + lane] = a;
}

// ---------------------------------------------------------------------------
// k_gpos: fused gather32 + lrelu + pos GEMV.
// wave/node: 2 edges per iter (halves), shfl combine; then 3-dot reduce.
// ---------------------------------------------------------------------------
__launch_bounds__(256)
__global__ void k_gpos(const int* __restrict__ ro, const int* __restrict__ csr,
                       const u16* __restrict__ t, const float* __restrict__ acc2,
                       const float* __restrict__ PW, const float* __restrict__ PB,
                       float* __restrict__ out)
{
    const int wid = (blockIdx.x << 2) | (threadIdx.x >> 6);
    if (wid >= N_NODES) return;
    const int lane = threadIdx.x & 63;
    const int half = lane >> 5, f = lane & 31;
    const int s = ro[wid], e = ro[wid + 1];
    float a = 0.f;
    int i = s;
    for (; i + 8 <= e; i += 8) {
        int s0 = csr[i + half], s1 = csr[i + 2 + half];
        int s2 = csr[i + 4 + half], s3 = csr[i + 6 + half];
        u16 v0 = t[(size_t)s0 * 32 + f], v1 = t[(size_t)s1 * 32 + f];
        u16 v2 = t[(size_t)s2 * 32 + f], v3 = t[(size_t)s3 * 32 + f];
        a += bf2f(v0); a += bf2f(v1); a += bf2f(v2); a += bf2f(v3);
    }
    for (; i < e; i += 2) {
        int idx = i + half;
        if (idx < e) a += bf2f(t[(size_t)csr[idx] * 32 + f]);
    }
    a += __shfl_xor(a, 32, 64);

    float v = lrelu(acc2[(size_t)wid * 32 + f] + a);
    float p0 = v * PW[f], p1 = v * PW[32 + f], p2 = v * PW[64 + f];
#pragma unroll
    for (int off = 16; off >= 1; off >>= 1) {
        p0 += __shfl_xor(p0, off, 64);
        p1 += __shfl_xor(p1, off, 64);
        p2 += __shfl_xor(p2, off, 64);
    }
    if (lane == 0) {
        out[(size_t)wid * 3 + 0] = p0 + PB[0];
        out[(size_t)wid * 3 + 1] = p1 + PB[1];
        out[(size_t)wid * 3 + 2] = p2 + PB[2];
    }
}

// ---------------------------------------------------------------------------
extern "C" void kernel_launch(void* const* d_in, const int* in_sizes, int n_in,
                              void* d_out, int out_size, void* d_ws, size_t ws_size,
                              hipStream_t stream)
{
    const float* x        = (const float*)d_in[0];
    const int*   ei       = (const int*)d_in[1];
    const float* lin1_w   = (const float*)d_in[2];
    const float* lin1_b   = (const float*)d_in[3];
    const float* c1_wrel  = (const float*)d_in[4];
    const float* c1_brel  = (const float*)d_in[5];
    const float* c1_wroot = (const float*)d_in[6];
    const float* c4_wrel  = (const float*)d_in[7];
    const float* c4_brel  = (const float*)d_in[8];
    const float* c4_wroot = (const float*)d_in[9];
    const float* pos_w    = (const float*)d_in[10];
    const float* pos_b    = (const float*)d_in[11];
    float* out = (float*)d_out;

    char* base = (char*)d_ws;
    u16*   h1b  = (u16*)base;                                   // 12.8 MB
    u16*   t1b  = (u16*)(base + 12800000);                      // 6.4 MB
    float* acc1 = (float*)(base + 12800000 + 6400000);          // 12.8 MB
    u16*   t2b  = (u16*)(base + 32000000);                      // 3.2 MB
    float* acc2 = (float*)(base + 35200000);                    // 6.4 MB
    u16*   wf1  = (u16*)(base + 41600000);                      // 512 KB
    u16*   wf2  = wf1 + 262144;
    u16*   wf3  = wf2 + 16384;
    int*   ibase = (int*)(wf3 + 4096);
    const int NPAD = ((N_NODES + 255) / 256) * 256;             // 50176
    int* deg  = ibase;
    int* tmp  = deg  + NPAD;
    int* ro   = tmp  + NPAD;
    int* cur  = ro   + NPAD;
    int* bsum = cur  + NPAD;
    int* boff = bsum + 256;
    int* csr  = boff + 256;
    const int NB = (N_NODES + 255) / 256;                       // 196

    // weight prep
    hipLaunchKernelGGL(k_wprep1, dim3(1024), dim3(256), 0, stream, lin1_w, wf1);
    hipLaunchKernelGGL(k_wprep2, dim3(64), dim3(256), 0, stream, c1_wrel, c1_wroot, wf2);
    hipLaunchKernelGGL(k_wprep3, dim3(16), dim3(256), 0, stream, c4_wrel, c4_wroot, wf3);

    // CSR build
    hipLaunchKernelGGL(k_zero, dim3(NB), dim3(256), 0, stream, deg, N_NODES);
    hipLaunchKernelGGL(k_hist, dim3(2048), dim3(256), 0, stream, ei, deg);
    hipLaunchKernelGGL(k_scan1, dim3(NB), dim3(256), 0, stream, deg, tmp, bsum);
    hipLaunchKernelGGL(k_scan2p, dim3(1), dim3(256), 0, stream, bsum, boff, NB);
    hipLaunchKernelGGL(k_scan3, dim3(NB), dim3(256), 0, stream, tmp, boff, deg, ro, cur);
    hipLaunchKernelGGL(k_fill, dim3(2048), dim3(256), 0, stream, ei, cur, csr);

    // 1) h1(bf16) = lrelu(x @ lin1_w.T + b)   [LDS-staged DMA GEMM]
    hipLaunchKernelGGL(k_lin1s, dim3((N_NODES + 63) / 64), dim3(256), 0, stream,
                       x, wf1, lin1_b, h1b);
    // 2) t1(bf16) / acc1(f32)
    hipLaunchKernelGGL(k_dualf1, dim3((N_NODES + 63) / 64), dim3(256), 0, stream,
                       h1b, wf2, c1_brel, t1b, acc1);
    // 3) acc1 += gather(t1)
    hipLaunchKernelGGL(k_gather64, dim3((N_NODES + 3) / 4), dim3(256), 0, stream,
                       ro, csr, t1b, acc1);
    // 4) t2(bf16) / acc2(f32)
    hipLaunchKernelGGL(k_dualf2, dim3((N_NODES + 63) / 64), dim3(256), 0, stream,
                       acc1, wf3, c4_brel, t2b, acc2);
    // 5) out = lrelu(acc2 + gather(t2)) @ pos_w.T + pos_b   [fused]
    hipLaunchKernelGGL(k_gpos, dim3((N_NODES + 3) / 4), dim3(256), 0, stream,
                       ro, csr, t2b, acc2, pos_w, pos_b, out);
}